// Round 10
// baseline (10946.562 us; speedup 1.0000x reference)
//
#include <hip/hip_runtime.h>

// LSTM-VAE  B=64 T=256 D=1024 L=2 G=128 — persistent kernel, decoupled waves:
// crit waves (gated half + in-register epilogue + per-wave arrivals) and aux
// waves (ready half -> LDS partial) run with ZERO __syncthreads in hot loop.
// h stored as row-contiguous coherent dwordx4. Rings + phase-edge fences kept.
#define B_  64
#define T_  256
#define D_  1024
#define G_  128
#define FD  4096   // 4*D
#define K2  2048   // D (ih) + D (hh)
#define BD  65536  // B_*D_
#define NWG 256
#define CL  128    // u32 stride between counter lines (512 B)

typedef unsigned short u16;
typedef __attribute__((ext_vector_type(8))) short frag8;  // 8 bf16
typedef __attribute__((ext_vector_type(4))) float f4;
typedef __attribute__((ext_vector_type(4))) int i4;

__device__ __forceinline__ u16 f2b(float f) {
  unsigned u = __float_as_uint(f);
  u += 0x7fffu + ((u >> 16) & 1u);
  return (u16)(u >> 16);
}
__device__ __forceinline__ float b2f(u16 s) {
  return __uint_as_float(((unsigned)s) << 16);
}
__device__ __forceinline__ float sigm(float x) { return 1.0f / (1.0f + __expf(-x)); }

__device__ __forceinline__ void stcoh4(void* p, i4 w) {
  asm volatile("global_store_dwordx4 %0, %1, off sc0 sc1"
               :: "v"(p), "v"(w) : "memory");
}

// ---------------- signal primitives -----------------------------------------
__device__ __forceinline__ void poll16_pub(const unsigned* s, unsigned tgt,
                                           unsigned* lf, unsigned seq) {
  const int l = threadIdx.x & 63;
  for (;;) {
    bool ok = true;
    if (l < 16)
      ok = __hip_atomic_load(&s[l * CL], __ATOMIC_RELAXED,
                             __HIP_MEMORY_SCOPE_AGENT) >= tgt;
    if (__all(ok)) break;
    __builtin_amdgcn_s_sleep(4);
  }
  if (l == 0)
    __hip_atomic_store(lf, seq, __ATOMIC_RELAXED, __HIP_MEMORY_SCOPE_WORKGROUP);
  asm volatile("" ::: "memory");
}

__device__ __forceinline__ void lds_wait(const unsigned* lf, unsigned seq) {
  while (__hip_atomic_load(lf, __ATOMIC_RELAXED,
                           __HIP_MEMORY_SCOPE_WORKGROUP) < seq)
    __builtin_amdgcn_s_sleep(1);
  asm volatile("" ::: "memory");
}

__device__ __forceinline__ void wg_arrive(unsigned* cnt, int wg) {
  asm volatile("s_waitcnt vmcnt(0)" ::: "memory");
  __syncthreads();
  if (threadIdx.x == 0)
    __hip_atomic_fetch_add(&cnt[(wg & 15) * CL], 1u, __ATOMIC_RELAXED,
                           __HIP_MEMORY_SCOPE_AGENT);
}

__device__ __forceinline__ void wave_wait16(const unsigned* cnt, unsigned tgt) {
  const int l = threadIdx.x & 63;
  if (l < 16) {
    while (__hip_atomic_load(&cnt[l * CL], __ATOMIC_RELAXED,
                             __HIP_MEMORY_SCOPE_AGENT) < tgt)
      __builtin_amdgcn_s_sleep(2);
  }
  asm volatile("" ::: "memory");
}

__device__ __forceinline__ void fullsync(unsigned* g, unsigned ep, int wg,
                                         bool fenced) {
  if (fenced) __builtin_amdgcn_fence(__ATOMIC_RELEASE, "agent");
  wg_arrive(g, wg);
  wave_wait16(g, ep * 16u);
  __syncthreads();
  if (fenced) {
    __builtin_amdgcn_fence(__ATOMIC_ACQUIRE, "agent");
    __syncthreads();
  }
}

// ---------------- weight slice load: 32 rows x 2048 bf16, XOR-swizzled ------
__device__ __forceinline__ void load_weights(const u16* __restrict__ Wg, char* wlds) {
  const int t  = threadIdx.x;
  const int r  = t >> 4;           // 0..31
  const int c0 = t & 15;
  const char* src = (const char*)(Wg + (long)r * K2);
  char* dstrow = wlds + (r << 12);
  const int swz = (r & 7) << 4;
  #pragma unroll
  for (int i = 0; i < 16; ++i) {
    const int cb = (c0 + (i << 4)) << 4;
    frag8 v = *(const frag8*)(src + cb);
    *(frag8*)(dstrow + (cb ^ swz)) = v;
  }
  __syncthreads();
}

// ---------------- MFMA half-block (one K-half, rows mt*16..+15, 32 cols) ----
__device__ __forceinline__ void half_mfma(const u16* A, int kofs, int mt,
                                          const char* wlds, f4& acc0, f4& acc1) {
  const int lane = threadIdx.x & 63;
  const int l15 = lane & 15, lgr = lane >> 4;
  const u16* ap = A + (mt * 16 + l15) * 1024 + lgr * 8;
  const int kbyte0 = kofs * 2 + (lgr << 4);
  const int swz = (l15 & 7) << 4;
  const char* w0r = wlds + ((long)l15 << 12);
  const char* w1r = wlds + ((long)(16 + l15) << 12);
  #pragma unroll 8
  for (int kk = 0; kk < 32; ++kk) {
    frag8 af = *(const frag8*)(ap + kk * 32);
    const int kb = (kbyte0 + (kk << 6)) ^ swz;
    frag8 b0 = *(const frag8*)(w0r + kb);
    frag8 b1 = *(const frag8*)(w1r + kb);
    acc0 = __builtin_amdgcn_mfma_f32_16x16x32_bf16(af, b0, acc0, 0, 0, 0);
    acc1 = __builtin_amdgcn_mfma_f32_16x16x32_bf16(af, b1, acc1, 0, 0, 0);
  }
}

// ---------------- aux wave: ready half -> LDS partial -----------------------
__device__ __forceinline__ void aux_step(
    const u16* A, const unsigned* sig, unsigned tgt, int kofs, int s,
    const char* wlds, float* gl, unsigned* lsf, unsigned* auxd, unsigned* critd,
    int mt)
{
  const int lane = threadIdx.x & 63;
  if (s >= 2) lds_wait(&critd[mt], (unsigned)(s - 1));   // gl WAR
  if (sig) {
    if (mt == 0) poll16_pub(sig, tgt, &lsf[1], (unsigned)(s + 1));
    else         lds_wait(&lsf[1], (unsigned)(s + 1));
  }
  f4 acc0 = (f4){0.f,0.f,0.f,0.f}, acc1 = (f4){0.f,0.f,0.f,0.f};
  if (A) half_mfma(A, kofs, mt, wlds, acc0, acc1);
  float* slot = gl + (((s & 1) * 4 + mt) << 9);          // 512 floats/slot
  #pragma unroll
  for (int r = 0; r < 4; ++r) {
    slot[r * 64 + lane]       = acc0[r];
    slot[(4 + r) * 64 + lane] = acc1[r];
  }
  asm volatile("s_waitcnt lgkmcnt(0)" ::: "memory");
  if (lane == 0)
    __hip_atomic_store(&auxd[mt], (unsigned)(s + 1), __ATOMIC_RELAXED,
                       __HIP_MEMORY_SCOPE_WORKGROUP);
}

// ---------------- crit wave: gated half + full epilogue + arrival -----------
__device__ __forceinline__ void crit_step(
    const u16* A, const unsigned* sig, unsigned tgt, int kofs, int s,
    const char* wlds, float* gl, unsigned* lsf, unsigned* auxd, unsigned* critd,
    int mt, int ug0, float& c0r, float& c1r, const f4& bq0, const f4& bq1,
    u16* __restrict__ hout, float* __restrict__ fout, long fstride,
    unsigned* arr, int wg)
{
  const int lane = threadIdx.x & 63;
  const int l15 = lane & 15, lgr = lane >> 4;
  const int g = l15 & 3, u0 = l15 >> 2;
  const int row = mt * 16 + lgr * 4 + g;

  if (sig) {
    if (mt == 0) poll16_pub(sig, tgt, &lsf[0], (unsigned)(s + 1));
    else         lds_wait(&lsf[0], (unsigned)(s + 1));
  }
  f4 acc0 = (f4){0.f,0.f,0.f,0.f}, acc1 = (f4){0.f,0.f,0.f,0.f};
  if (A) half_mfma(A, kofs, mt, wlds, acc0, acc1);

  lds_wait(&auxd[mt], (unsigned)(s + 1));
  __builtin_amdgcn_sched_barrier(0);
  const float* slot = gl + (((s & 1) * 4 + mt) << 9);
  #pragma unroll
  for (int r = 0; r < 4; ++r) {
    acc0[r] += slot[r * 64 + lane];
    acc1[r] += slot[(4 + r) * 64 + lane];
  }
  asm volatile("s_waitcnt lgkmcnt(0)" ::: "memory");
  __builtin_amdgcn_sched_barrier(0);
  if (lane == 0)
    __hip_atomic_store(&critd[mt], (unsigned)(s + 1), __ATOMIC_RELAXED,
                       __HIP_MEMORY_SCOPE_WORKGROUP);

  // in-register epilogue: gather gate quads via shfl_xor within 4-lane groups
  unsigned hv0 = 0, hv1 = 0; float hf0 = 0.f, hf1 = 0.f;
  #pragma unroll
  for (int r = 0; r < 4; ++r) {
    {
      float a = acc0[r];
      float b = __shfl_xor(a, 1), c = __shfl_xor(a, 2), d = __shfl_xor(a, 3);
      if (g == r) {
        float iv, fv, gv, ov;
        if      (r == 0) { iv = a; fv = b; gv = c; ov = d; }
        else if (r == 1) { iv = b; fv = a; gv = d; ov = c; }
        else if (r == 2) { iv = c; fv = d; gv = a; ov = b; }
        else             { iv = d; fv = c; gv = b; ov = a; }
        iv += bq0.x; fv += bq0.y; gv += bq0.z; ov += bq0.w;
        float cn = sigm(fv) * c0r + sigm(iv) * tanhf(gv);
        float hh = sigm(ov) * tanhf(cn);
        c0r = cn; hv0 = (unsigned)f2b(hh); hf0 = hh;
      }
    }
    {
      float a = acc1[r];
      float b = __shfl_xor(a, 1), c = __shfl_xor(a, 2), d = __shfl_xor(a, 3);
      if (g == r) {
        float iv, fv, gv, ov;
        if      (r == 0) { iv = a; fv = b; gv = c; ov = d; }
        else if (r == 1) { iv = b; fv = a; gv = d; ov = c; }
        else if (r == 2) { iv = c; fv = d; gv = a; ov = b; }
        else             { iv = d; fv = c; gv = b; ov = a; }
        iv += bq1.x; fv += bq1.y; gv += bq1.z; ov += bq1.w;
        float cn = sigm(fv) * c1r + sigm(iv) * tanhf(gv);
        float hh = sigm(ov) * tanhf(cn);
        c1r = cn; hv1 = (unsigned)f2b(hh); hf1 = hh;
      }
    }
  }
  // pack full row (8 units = 16B) into one coherent dwordx4
  unsigned p0  = __shfl_xor(hv0, 4);        // unit u0^1
  unsigned p1  = __shfl_xor(hv1, 4);
  unsigned wA  = hv0 | (p0 << 16);          // units (u0, u0+1)   [even u0]
  unsigned wB  = hv1 | (p1 << 16);          // units (u0+4, u0+5) [even u0]
  unsigned wA2 = __shfl_xor(wA, 8);         // from lane u0^2
  unsigned wB2 = __shfl_xor(wB, 8);
  if (u0 == 0) {
    i4 w; w.x = (int)wA; w.y = (int)wA2; w.z = (int)wB; w.w = (int)wB2;
    stcoh4(hout + row * 1024 + ug0, w);
  }
  if (fout) {
    fout[(long)row * fstride + ug0 + u0]     = hf0;
    fout[(long)row * fstride + ug0 + u0 + 4] = hf1;
  }
  asm volatile("s_waitcnt vmcnt(0)" ::: "memory");
  if (lane == 0)
    __hip_atomic_fetch_add(&arr[(wg & 15) * CL], 1u, __ATOMIC_RELAXED,
                           __HIP_MEMORY_SCOPE_AGENT);
}

// ---------------- VAE head, one (s,l,b) per WG ------------------------------
__device__ __forceinline__ void vae_wg(
    int bid, char* scr,
    const u16* h0f, const u16* h1f, const float* c0f, const float* c1f,
    const float* hmuW, const float* hmub, const float* hsgW, const float* hsgb,
    const float* houtW, const float* houtb,
    const float* cmuW, const float* cmub, const float* csgW, const float* csgb,
    const float* coutW, const float* coutb,
    const float* eps_h, const float* eps_c,
    float* muo, float* sgo, u16* hd0, u16* hd1, float* cd0, float* cd1)
{
  float* hrow = (float*)scr;
  float* muv  = hrow + 1024;
  float* sgv  = muv + 128;
  float* zz   = sgv + 128;
  const int tid = threadIdx.x;
  const int b = bid & 63, l = (bid >> 6) & 1, s = bid >> 7;

  if (s == 0) {
    const u16* h = (l ? h1f : h0f) + b * D_;
    for (int i = tid; i < D_; i += 512) hrow[i] = b2f(h[i]);
  } else {
    const float* c = (l ? c1f : c0f) + b * D_;
    for (int i = tid; i < D_; i += 512) hrow[i] = c[i];
  }
  __syncthreads();

  const float* muW = (s ? cmuW : hmuW) + (long)l * G_ * D_;
  const float* sgW = (s ? csgW : hsgW) + (long)l * G_ * D_;
  const float* mub = (s ? cmub : hmub) + l * G_;
  const float* sgb = (s ? csgb : hsgb) + l * G_;
  const int wv = tid >> 6, lane = tid & 63;
  for (int oi = wv; oi < 2 * G_; oi += 8) {
    const int g = (oi < G_) ? oi : oi - G_;
    const float* Wr = ((oi < G_) ? muW : sgW) + (long)g * D_;
    float d = 0.f;
    for (int j = lane; j < D_; j += 64) d += Wr[j] * hrow[j];
    for (int off = 1; off < 64; off <<= 1) d += __shfl_xor(d, off);
    if (lane == 0) {
      if (oi < G_) muv[g] = d + mub[g]; else sgv[g] = d + sgb[g];
    }
  }
  __syncthreads();
  if (tid < G_) {
    const int g = tid;
    const float mu = muv[g], sg = sgv[g];
    const float* ep = (s ? eps_c : eps_h) + ((long)l * B_ + b) * G_;
    zz[g] = mu + ep[g] * __expf(sg);
    muo[(long)bid * G_ + g] = mu;
    sgo[(long)bid * G_ + g] = sg;
  }
  __syncthreads();
  const float* oW  = (s ? coutW : houtW) + (long)l * D_ * G_;
  const float* obv = (s ? coutb : houtb) + l * D_;
  for (int i = 0; i < 2; ++i) {
    const int dd = i * 512 + tid;
    float acc = obv[dd];
    const float* Wr = oW + (long)dd * G_;
    #pragma unroll 4
    for (int g = 0; g < G_; ++g) acc += zz[g] * Wr[g];
    if (s == 0) { (l ? hd1 : hd0)[b * D_ + dd] = f2b(acc); }
    else        { (l ? cd1 : cd0)[b * D_ + dd] = acc; }
  }
  __syncthreads();
}

// ---------------- the persistent kernel -------------------------------------
__global__ __launch_bounds__(512, 1)
void persist(const u16* __restrict__ Wpe, const u16* __restrict__ Wpd,
             const float* __restrict__ bp,
             const u16* __restrict__ xb, const u16* __restrict__ xd0,
             u16* ring0, u16* ring1,
             float* ce0, float* ce1,
             u16* hd0i, u16* hd1i, float* cd0, float* cd1,
             const float* hmuW, const float* hmub, const float* hsgW, const float* hsgb,
             const float* houtW, const float* houtb,
             const float* cmuW, const float* cmub, const float* csgW, const float* csgb,
             const float* coutW, const float* coutb,
             const float* eps_h, const float* eps_c,
             float* out, float* muo, float* sgo, unsigned* bar)
{
  __shared__ __align__(16) char smem[147520];  // 128K weights + 16K gl + flags
  char*  wlds = smem;
  float* gl   = (float*)(smem + 131072);       // 8 slots x 512 floats
  unsigned* lsf   = (unsigned*)(smem + 147456);       // [0]=crit,[1]=aux
  unsigned* auxd  = (unsigned*)(smem + 147456 + 8);   // [4]
  unsigned* critd = (unsigned*)(smem + 147456 + 24);  // [4]

  unsigned* gcnt = bar;
  unsigned* acnt = bar + 2048;
  unsigned* bcnt = bar + 4096;
  unsigned* ccnt = bar + 6144;
  unsigned* dcnt = bar + 8192;

  const int wg  = blockIdx.x;
  const bool isL0 = (wg < 128);
  const int wgL = wg & 127;
  const int ug0 = wgL * 8;
  const int tid = threadIdx.x;
  const int wv  = tid >> 6;
  const bool isCrit = (wv < 4);
  const int mt = wv & 3;
  const int lane = tid & 63;
  const int u0 = (lane & 15) >> 2, g = lane & 3;
  const int row = mt * 16 + (lane >> 4) * 4 + g;

  // ---- encoder phase ----
  if (tid == 0) { lsf[0]=0; lsf[1]=0; auxd[0]=auxd[1]=auxd[2]=auxd[3]=0;
                  critd[0]=critd[1]=critd[2]=critd[3]=0; }
  load_weights(Wpe + (isL0 ? 0l : (long)FD * K2) + (long)wgL * 32 * K2, wlds);
  const float* bpe = bp + (isL0 ? 0 : FD);
  f4 bq0 = *(const f4*)(bpe + (ug0 + u0) * 4);
  f4 bq1 = *(const f4*)(bpe + (ug0 + u0 + 4) * 4);
  float c0r = 0.f, c1r = 0.f;

  if (isL0) {
    if (isCrit) {
      for (int s = 0; s < T_; ++s)
        crit_step(s ? (ring0 + (long)(s-1) * BD) : nullptr,
                  s ? acnt : nullptr, 32u * (unsigned)s, 1024, s,
                  wlds, gl, lsf, auxd, critd, mt, ug0, c0r, c1r, bq0, bq1,
                  ring0 + (long)s * BD, nullptr, 0, acnt, wg);
    } else {
      for (int s = 0; s < T_; ++s)
        aux_step(xb + (long)s * BD, nullptr, 0, 0, s,
                 wlds, gl, lsf, auxd, critd, mt);
    }
  } else {
    if (isCrit) {
      for (int t = 0; t < T_; ++t)
        crit_step(ring0 + (long)t * BD, acnt, 32u * (unsigned)(t + 1), 0, t,
                  wlds, gl, lsf, auxd, critd, mt, ug0, c0r, c1r, bq0, bq1,
                  ring1 + (long)t * BD, nullptr, 0, bcnt, wg);
    } else {
      for (int t = 0; t < T_; ++t)
        aux_step(t ? (ring1 + (long)(t-1) * BD) : nullptr,
                 t ? bcnt : nullptr, 32u * (unsigned)t, 1024, t,
                 wlds, gl, lsf, auxd, critd, mt);
    }
  }
  // publish final c (crit lanes own it; normal stores; fenced sync follows)
  if (isCrit) {
    float* ce = isL0 ? ce0 : ce1;
    ce[row * D_ + ug0 + u0]     = c0r;
    ce[row * D_ + ug0 + u0 + 4] = c1r;
  }
  fullsync(gcnt, 1, wg, true);

  // ---- VAE ----
  vae_wg(wg, (char*)gl,
         ring0 + 255l * BD, ring1 + 255l * BD, ce0, ce1,
         hmuW, hmub, hsgW, hsgb, houtW, houtb,
         cmuW, cmub, csgW, csgb, coutW, coutb,
         eps_h, eps_c, muo, sgo, hd0i, hd1i, cd0, cd1);
  fullsync(gcnt, 2, wg, true);

  // ---- decoder phase ----
  if (tid == 0) { lsf[0]=0; lsf[1]=0; auxd[0]=auxd[1]=auxd[2]=auxd[3]=0;
                  critd[0]=critd[1]=critd[2]=critd[3]=0; }
  load_weights(Wpd + (isL0 ? 0l : (long)FD * K2) + (long)wgL * 32 * K2, wlds);
  const float* bpd = bp + 2 * FD + (isL0 ? 0 : FD);
  bq0 = *(const f4*)(bpd + (ug0 + u0) * 4);
  bq1 = *(const f4*)(bpd + (ug0 + u0 + 4) * 4);
  if (isCrit) {
    const float* cd = isL0 ? cd0 : cd1;
    c0r = cd[row * D_ + ug0 + u0];
    c1r = cd[row * D_ + ug0 + u0 + 4];
  }
  __syncthreads();   // flags visible before hot loop

  if (isL0) {
    if (isCrit) {
      for (int t = 0; t < T_; ++t)
        crit_step(t ? (ring1 + (long)(t-1) * BD) : xd0,
                  t ? dcnt : nullptr, 32u * (unsigned)t, 0, t,
                  wlds, gl, lsf, auxd, critd, mt, ug0, c0r, c1r, bq0, bq1,
                  ring0 + (long)t * BD, nullptr, 0, ccnt, wg);
    } else {
      for (int t = 0; t < T_; ++t)
        aux_step(t ? (ring0 + (long)(t-1) * BD) : hd0i,
                 t ? ccnt : nullptr, 32u * (unsigned)t, 1024, t,
                 wlds, gl, lsf, auxd, critd, mt);
    }
  } else {
    if (isCrit) {
      for (int t = 0; t < T_; ++t)
        crit_step(ring0 + (long)t * BD, ccnt, 32u * (unsigned)(t + 1), 0, t,
                  wlds, gl, lsf, auxd, critd, mt, ug0, c0r, c1r, bq0, bq1,
                  ring1 + (long)t * BD, out + (long)t * D_, (long)T_ * D_,
                  dcnt, wg);
    } else {
      for (int t = 0; t < T_; ++t)
        aux_step(t ? (ring1 + (long)(t-1) * BD) : hd1i,
                 t ? dcnt : nullptr, 32u * (unsigned)t, 1024, t,
                 wlds, gl, lsf, auxd, critd, mt);
    }
  }
}

// ---------------------------------------------------------------------------
// Spectral norm prepass (unchanged, verified)
// ---------------------------------------------------------------------------
__device__ __forceinline__ const float* selW(int m, const float* a, const float* b,
                                             const float* c, const float* d) {
  const float* W;
  switch (m >> 1) { case 0: W = a; break; case 1: W = b; break;
                    case 2: W = c; break; default: W = d; }
  return W + (long)(m & 1) * FD * D_;
}
__device__ __forceinline__ const float* selU(int m, const float* a, const float* b,
                                             const float* c, const float* d) {
  const float* u;
  switch (m >> 1) { case 0: u = a; break; case 1: u = b; break;
                    case 2: u = c; break; default: u = d; }
  return u + (m & 1) * FD;
}

__global__ __launch_bounds__(256)
void k_unorm(const float* euih, const float* euhh, const float* duih, const float* duhh,
             float* uinv)
{
  const int m = blockIdx.x;
  const float* u = selU(m, euih, euhh, duih, duhh);
  float s = 0.f;
  for (int i = threadIdx.x; i < FD; i += 256) { float v = u[i]; s += v * v; }
  __shared__ float red[4];
  for (int off = 1; off < 64; off <<= 1) s += __shfl_xor(s, off);
  if ((threadIdx.x & 63) == 0) red[threadIdx.x >> 6] = s;
  __syncthreads();
  if (threadIdx.x == 0)
    uinv[m] = 1.0f / (sqrtf(red[0] + red[1] + red[2] + red[3]) + 1e-12f);
}

__global__ __launch_bounds__(256)
void k_v(const float* eWih, const float* eWhh, const float* dWih, const float* dWhh,
         const float* euih, const float* euhh, const float* duih, const float* duhh,
         const float* uinv, float* v, float* vss)
{
  __shared__ float us[FD];
  __shared__ float red[4];
  const int m = blockIdx.x >> 2, cb = blockIdx.x & 3;
  const float* W = selW(m, eWih, eWhh, dWih, dWhh);
  const float* u = selU(m, euih, euhh, duih, duhh);
  for (int i = threadIdx.x; i < FD; i += 256) us[i] = u[i];
  __syncthreads();
  const int j = cb * 256 + threadIdx.x;
  float acc = 0.f;
  for (int i = 0; i < FD; ++i) acc += W[(long)i * D_ + j] * us[i];
  acc *= uinv[m];
  v[m * D_ + j] = acc;
  float s = acc * acc;
  for (int off = 1; off < 64; off <<= 1) s += __shfl_xor(s, off);
  if ((threadIdx.x & 63) == 0) red[threadIdx.x >> 6] = s;
  __syncthreads();
  if (threadIdx.x == 0) vss[blockIdx.x] = red[0] + red[1] + red[2] + red[3];
}

__global__ __launch_bounds__(256)
void k_sig(const float* eWih, const float* eWhh, const float* dWih, const float* dWhh,
           const float* v, float* sgp)
{
  __shared__ float vl[D_];
  __shared__ float red[4];
  const int m = blockIdx.x >> 6, rb = blockIdx.x & 63;
  const float* W = selW(m, eWih, eWhh, dWih, dWhh);
  for (int i = threadIdx.x; i < D_; i += 256) vl[i] = v[m * D_ + i];
  __syncthreads();
  const int wv = threadIdx.x >> 6, lane = threadIdx.x & 63;
  float ssq = 0.f;
  for (int rr = 0; rr < 16; ++rr) {
    const int r = rb * 64 + wv * 16 + rr;
    const float* Wr = W + (long)r * D_;
    float d = 0.f;
    for (int j = lane; j < D_; j += 64) d += Wr[j] * vl[j];
    for (int off = 1; off < 64; off <<= 1) d += __shfl_xor(d, off);
    ssq += d * d;
  }
  if (lane == 0) red[wv] = ssq;
  __syncthreads();
  if (threadIdx.x == 0) sgp[blockIdx.x] = red[0] + red[1] + red[2] + red[3];
}

__global__ void k_fin(const float* vss, const float* sgp, float* rsig)
{
  const int m = threadIdx.x;
  if (m < 8) {
    float vn = sqrtf(vss[m * 4] + vss[m * 4 + 1] + vss[m * 4 + 2] + vss[m * 4 + 3]);
    float s2 = 0.f;
    for (int i = 0; i < 64; ++i) s2 += sgp[m * 64 + i];
    rsig[m] = (vn + 1e-12f) / sqrtf(s2);   // 1/sigma
  }
}

__global__ __launch_bounds__(256)
void k_pack(const float* eWih, const float* eWhh, const float* dWih, const float* dWhh,
            const float* rsig, u16* Wpe, u16* Wpd)
{
  const long idx = (long)blockIdx.x * 256 + threadIdx.x;
  const int k8   = (int)(idx & 255);
  const int np   = (int)((idx >> 8) & 4095);
  const int pair = (int)(idx >> 20);
  const int l = pair & 1, ed = pair >> 1;
  const int u = np >> 2, g = np & 3;
  const int srow = g * D_ + u;
  const int k = k8 * 8;
  const float* src; float sc;
  if (k < D_) {
    const float* Wih = ed ? dWih : eWih;
    src = Wih + ((long)(l * FD + srow)) * D_ + k;
    sc  = rsig[ed ? 4 + l : l];
  } else {
    const float* Whh = ed ? dWhh : eWhh;
    src = Whh + ((long)(l * FD + srow)) * D_ + (k - D_);
    sc  = rsig[ed ? 6 + l : 2 + l];
  }
  f4 a = *(const f4*)src;
  f4 b = *(const f4*)(src + 4);
  frag8 o;
  o[0] = (short)f2b(a.x * sc); o[1] = (short)f2b(a.y * sc);
  o[2] = (short)f2b(a.z * sc); o[3] = (short)f2b(a.w * sc);
  o[4] = (short)f2b(b.x * sc); o[5] = (short)f2b(b.y * sc);
  o[6] = (short)f2b(b.z * sc); o[7] = (short)f2b(b.w * sc);
  u16* dst = (ed ? Wpd : Wpe) + ((long)(l * FD + np)) * K2 + k;
  *(frag8*)dst = o;
}

__global__ void k_packb(const float* eb, const float* db, float* bp)
{
  const int idx = blockIdx.x * 256 + threadIdx.x;   // 4*4096
  const int j = idx & 4095, pair = idx >> 12;
  const int l = pair & 1, ed = pair >> 1;
  const float* b = (ed ? db : eb) + l * FD;
  bp[pair * FD + j] = b[(j & 3) * D_ + (j >> 2)];
}

// x [B,T,D] f32 -> xb [T][B][D] bf16
__global__ __launch_bounds__(512)
void k_xb(const float* __restrict__ x, u16* __restrict__ xb)
{
  const long i8 = ((long)blockIdx.x * 512 + threadIdx.x) * 8;
  const int d  = (int)(i8 & 1023);
  const int bt = (int)(i8 >> 10);
  const int b = bt & 63, t = bt >> 6;
  const float* src = x + ((long)b * T_ + t) * D_ + d;
  f4 a = *(const f4*)src;
  f4 c = *(const f4*)(src + 4);
  frag8 o;
  o[0] = (short)f2b(a.x); o[1] = (short)f2b(a.y);
  o[2] = (short)f2b(a.z); o[3] = (short)f2b(a.w);
  o[4] = (short)f2b(c.x); o[5] = (short)f2b(c.y);
  o[6] = (short)f2b(c.z); o[7] = (short)f2b(c.w);
  *(frag8*)(xb + i8) = o;
}

__global__ __launch_bounds__(512)
void k_xd0(const float* __restrict__ initial, u16* __restrict__ xd0)
{
  const int i8 = (blockIdx.x * 512 + threadIdx.x) * 8;   // < 65536
  const int d = i8 & 1023;
  f4 a = *(const f4*)(initial + d);
  f4 c = *(const f4*)(initial + d + 4);
  frag8 o;
  o[0] = (short)f2b(a.x); o[1] = (short)f2b(a.y);
  o[2] = (short)f2b(a.z); o[3] = (short)f2b(a.w);
  o[4] = (short)f2b(c.x); o[5] = (short)f2b(c.y);
  o[6] = (short)f2b(c.z); o[7] = (short)f2b(c.w);
  *(frag8*)(xd0 + i8) = o;
}

// ---------------------------------------------------------------------------
extern "C" void kernel_launch(void* const* d_in, const int* in_sizes, int n_in,
                              void* d_out, int out_size, void* d_ws, size_t ws_size,
                              hipStream_t stream)
{
  const float* x       = (const float*)d_in[0];
  const float* initial = (const float*)d_in[1];
  const float* eWih    = (const float*)d_in[2];
  const float* eWhh    = (const float*)d_in[3];
  const float* eb      = (const float*)d_in[4];
  const float* euih    = (const float*)d_in[5];
  const float* euhh    = (const float*)d_in[6];
  const float* dWih    = (const float*)d_in[7];
  const float* dWhh    = (const float*)d_in[8];
  const float* db      = (const float*)d_in[9];
  const float* duih    = (const float*)d_in[10];
  const float* duhh    = (const float*)d_in[11];
  const float* hmuW    = (const float*)d_in[12];
  const float* hmub    = (const float*)d_in[13];
  const float* hsgW    = (const float*)d_in[14];
  const float* hsgb    = (const float*)d_in[15];
  const float* houtW   = (const float*)d_in[16];
  const float* houtb   = (const float*)d_in[17];
  const float* cmuW    = (const float*)d_in[18];
  const float* cmub    = (const float*)d_in[19];
  const float* csgW    = (const float*)d_in[20];
  const float* csgb    = (const float*)d_in[21];
  const float* coutW   = (const float*)d_in[22];
  const float* coutb   = (const float*)d_in[23];
  const float* eps_h   = (const float*)d_in[24];
  const float* eps_c   = (const float*)d_in[25];

  char* w = (char*)d_ws;
  auto alloc = [&](size_t n) -> char* {
    char* p = w; w += (n + 255) & ~(size_t)255; return p;
  };
  u16*   Wpe   = (u16*)  alloc(2l * FD * K2 * 2);       // 32 MB
  u16*   Wpd   = (u16*)  alloc(2l * FD * K2 * 2);       // 32 MB
  u16*   xb    = (u16*)  alloc((long)T_ * BD * 2);      // 32 MB
  u16*   ring0 = (u16*)  alloc((long)T_ * BD * 2);      // 32 MB
  u16*   ring1 = (u16*)  alloc((long)T_ * BD * 2);      // 32 MB
  u16*   xd0   = (u16*)  alloc((long)BD * 2);
  u16*   hd0i  = (u16*)  alloc((long)BD * 2);
  u16*   hd1i  = (u16*)  alloc((long)BD * 2);
  float* ce0   = (float*)alloc((long)BD * 4);
  float* ce1   = (float*)alloc((long)BD * 4);
  float* cd0   = (float*)alloc((long)BD * 4);
  float* cd1   = (float*)alloc((long)BD * 4);
  float* bp    = (float*)alloc(4l * FD * 4);
  float* vv    = (float*)alloc(8l * D_ * 4);
  float* uinv  = (float*)alloc(64);
  float* vss   = (float*)alloc(256);
  float* sgp   = (float*)alloc(4096);
  float* rsig  = (float*)alloc(64);
  unsigned* bar = (unsigned*)alloc(40960);   // 5 sets x 16 lines x 512B

  hipMemsetAsync(bar, 0, 40960, stream);

  k_unorm<<<8,    256, 0, stream>>>(euih, euhh, duih, duhh, uinv);
  k_v    <<<32,   256, 0, stream>>>(eWih, eWhh, dWih, dWhh, euih, euhh, duih, duhh,
                                    uinv, vv, vss);
  k_sig  <<<512,  256, 0, stream>>>(eWih, eWhh, dWih, dWhh, vv, sgp);
  k_fin  <<<1,    64,  0, stream>>>(vss, sgp, rsig);
  k_pack <<<16384,256, 0, stream>>>(eWih, eWhh, dWih, dWhh, rsig, Wpe, Wpd);
  k_packb<<<64,   256, 0, stream>>>(eb, db, bp);
  k_xb   <<<4096, 512, 0, stream>>>(x, xb);
  k_xd0  <<<16,   512, 0, stream>>>(initial, xd0);

  float* out = (float*)d_out;
  float* muo = out + (long)B_ * T_ * D_;
  float* sgo = muo + 4l * B_ * G_;

  persist<<<NWG, 512, 0, stream>>>(Wpe, Wpd, bp, xb, xd0,
                                   ring0, ring1,
                                   ce0, ce1, hd0i, hd1i, cd0, cd1,
                                   hmuW, hmub, hsgW, hsgb, houtW, houtb,
                                   cmuW, cmub, csgW, csgb, coutW, coutb,
                                   eps_h, eps_c, out, muo, sgo, bar);
}

// Round 11
// 6680.664 us; speedup vs baseline: 1.6385x; 1.6385x over previous
//
#include <hip/hip_runtime.h>

// LSTM-VAE  B=64 T=256 D=1024 L=2 G=128 — persistent kernel, signal-driven
// (round-9 structure). Round 11: faster crit polls (sleep 1) + row-contiguous
// dwordx4 coherent h-stores (4 shfl_xor pack) to shorten the arrival drain.
#define B_  64
#define T_  256
#define D_  1024
#define G_  128
#define FD  4096   // 4*D
#define K2  2048   // D (ih) + D (hh)
#define BD  65536  // B_*D_
#define NWG 256
#define CL  128    // u32 stride between counter lines (512 B)

typedef unsigned short u16;
typedef __attribute__((ext_vector_type(8))) short frag8;  // 8 bf16
typedef __attribute__((ext_vector_type(4))) float f4;
typedef __attribute__((ext_vector_type(4))) int i4;

__device__ __forceinline__ u16 f2b(float f) {
  unsigned u = __float_as_uint(f);
  u += 0x7fffu + ((u >> 16) & 1u);
  return (u16)(u >> 16);
}
__device__ __forceinline__ float b2f(u16 s) {
  return __uint_as_float(((unsigned)s) << 16);
}
__device__ __forceinline__ float sigm(float x) { return 1.0f / (1.0f + __expf(-x)); }

// write-through coherent 16B store (lands at LLC once vmcnt drains)
__device__ __forceinline__ void stcoh4(void* p, i4 w) {
  asm volatile("global_store_dwordx4 %0, %1, off sc0 sc1"
               :: "v"(p), "v"(w) : "memory");
}

// ---------------- group-signal primitives -----------------------------------
// Poller wave: lanes 0..15 poll 16 counter lines; when ALL >= tgt, lane 0
// publishes seq to the LDS flag. Whole wave returns.
__device__ __forceinline__ void poll16_pub(const unsigned* s, unsigned tgt,
                                           unsigned* lf, unsigned seq) {
  const int l = threadIdx.x & 63;
  for (;;) {
    bool ok = true;
    if (l < 16)
      ok = __hip_atomic_load(&s[l * CL], __ATOMIC_RELAXED,
                             __HIP_MEMORY_SCOPE_AGENT) >= tgt;
    if (__all(ok)) break;
    __builtin_amdgcn_s_sleep(1);
  }
  if (l == 0)
    __hip_atomic_store(lf, seq, __ATOMIC_RELAXED, __HIP_MEMORY_SCOPE_WORKGROUP);
  asm volatile("" ::: "memory");
}

// Sibling waves: spin on the LDS flag (no fabric traffic).
__device__ __forceinline__ void lds_wait(const unsigned* lf, unsigned seq) {
  while (__hip_atomic_load(lf, __ATOMIC_RELAXED,
                           __HIP_MEMORY_SCOPE_WORKGROUP) < seq)
    __builtin_amdgcn_s_sleep(1);
  asm volatile("" ::: "memory");
}

// arrive: drain this WG's (coherent) stores, then one atomic add.
__device__ __forceinline__ void wg_arrive(unsigned* cnt, int wg) {
  asm volatile("s_waitcnt vmcnt(0)" ::: "memory");
  __syncthreads();
  if (threadIdx.x == 0)
    __hip_atomic_fetch_add(&cnt[(wg & 15) * CL], 1u, __ATOMIC_RELAXED,
                           __HIP_MEMORY_SCOPE_AGENT);
}

// full-wave poll for phase-edge syncs (rare; contention irrelevant there)
__device__ __forceinline__ void wave_wait16(const unsigned* cnt, unsigned tgt) {
  const int l = threadIdx.x & 63;
  if (l < 16) {
    while (__hip_atomic_load(&cnt[l * CL], __ATOMIC_RELAXED,
                             __HIP_MEMORY_SCOPE_AGENT) < tgt)
      __builtin_amdgcn_s_sleep(2);
  }
  asm volatile("" ::: "memory");
}

// full-grid sync (phase edges only); fenced = release/acquire cache ops
__device__ __forceinline__ void fullsync(unsigned* g, unsigned ep, int wg,
                                         bool fenced) {
  if (fenced) __builtin_amdgcn_fence(__ATOMIC_RELEASE, "agent");
  wg_arrive(g, wg);
  wave_wait16(g, ep * 16u);
  __syncthreads();
  if (fenced) {
    __builtin_amdgcn_fence(__ATOMIC_ACQUIRE, "agent");
    __syncthreads();
  }
}

// ---------------- weight slice load: 32 rows x 2048 bf16, XOR-swizzled ------
__device__ __forceinline__ void load_weights(const u16* __restrict__ Wg, char* wlds) {
  const int t  = threadIdx.x;
  const int r  = t >> 4;           // 0..31
  const int c0 = t & 15;
  const char* src = (const char*)(Wg + (long)r * K2);
  char* dstrow = wlds + (r << 12);
  const int swz = (r & 7) << 4;
  #pragma unroll
  for (int i = 0; i < 16; ++i) {
    const int cb = (c0 + (i << 4)) << 4;      // chunk byte offset
    frag8 v = *(const frag8*)(src + cb);
    *(frag8*)(dstrow + (cb ^ swz)) = v;
  }
  __syncthreads();
}

// ---------------- one LSTM cell with LDS-mediated dependency waits ----------
// A0 (k<1024) gated by (c0p,t0); A1 (k>=1024) by (c1p,t1). null = ready.
// Wave 0 polls sig0, wave 4 polls sig1; waves 1-3 / 5-7 spin on LDS flags.
__device__ __forceinline__ void cellw(
    const u16* __restrict__ A0, const unsigned* c0p, unsigned t0,
    const u16* __restrict__ A1, const unsigned* c1p, unsigned t1,
    const char* wlds, float* gl, unsigned* lsf, unsigned seq,
    float& c_reg, const f4& bias, int ug0,
    u16* __restrict__ hout, float* __restrict__ fout, long fstride)
{
  const int tid = threadIdx.x;
  const int lane = tid & 63, wv = tid >> 6;
  const int mt = wv & 3, kh = wv >> 2;
  const int l15 = lane & 15, lgr = lane >> 4;

  f4 acc0 = (f4){0.f,0.f,0.f,0.f}, acc1 = (f4){0.f,0.f,0.f,0.f};
  const u16* Ab = kh ? A1 : A0;
  const unsigned* cp = kh ? c1p : c0p;
  const unsigned tg  = kh ? t1 : t0;
  unsigned* lf = lsf + kh;
  if (Ab) {
    if (cp) {
      if (mt == 0) poll16_pub(cp, tg, lf, seq);   // waves 0 and 4
      else         lds_wait(lf, seq);             // siblings: LDS spin
    }
    const u16* ap = Ab + (mt * 16 + l15) * 1024 + lgr * 8;
    const int kbyte0 = (kh << 11) + (lgr << 4);
    const int swz = (l15 & 7) << 4;
    const char* w0r = wlds + ((long)l15 << 12);
    const char* w1r = wlds + ((long)(16 + l15) << 12);
    #pragma unroll 8
    for (int kk = 0; kk < 32; ++kk) {
      frag8 af = *(const frag8*)(ap + kk * 32);
      const int kb = (kbyte0 + (kk << 6)) ^ swz;
      frag8 b0 = *(const frag8*)(w0r + kb);
      frag8 b1 = *(const frag8*)(w1r + kb);
      acc0 = __builtin_amdgcn_mfma_f32_16x16x32_bf16(af, b0, acc0, 0, 0, 0);
      acc1 = __builtin_amdgcn_mfma_f32_16x16x32_bf16(af, b1, acc1, 0, 0, 0);
    }
  }
  float* g = gl + kh * (64 * 32);
  const int orow = mt * 16 + lgr * 4;
  #pragma unroll
  for (int r = 0; r < 4; ++r) {
    g[(orow + r) * 32 + l15]      = acc0[r];
    g[(orow + r) * 32 + 16 + l15] = acc1[r];
  }
  __syncthreads();

  const int row = tid >> 3, ul = tid & 7;
  f4 p0 = *(const f4*)(gl + row * 32 + ul * 4);
  f4 p1 = *(const f4*)(gl + 64 * 32 + row * 32 + ul * 4);
  float iv = p0.x + p1.x + bias.x;
  float fv = p0.y + p1.y + bias.y;
  float gv = p0.z + p1.z + bias.z;
  float ov = p0.w + p1.w + bias.w;
  float cn = sigm(fv) * c_reg + sigm(iv) * tanhf(gv);
  float hh = sigm(ov) * tanhf(cn);
  c_reg = cn;
  // pack the 8-unit row (16B) with 4 shfl_xor; one dwordx4 per row (ul==0)
  unsigned hv = (unsigned)f2b(hh);
  unsigned a  = hv | (__shfl_xor(hv, 1) << 16);   // (u, u+1) at even ul
  unsigned b  = __shfl_xor(a, 2);                 // (u2,u3) at ul0
  unsigned c2 = __shfl_xor(a, 4);                 // (u4,u5) at ul0
  unsigned d2 = __shfl_xor(b, 4);                 // (u6,u7) at ul0
  if (ul == 0) {
    i4 w; w.x = (int)a; w.y = (int)b; w.z = (int)c2; w.w = (int)d2;
    stcoh4(hout + row * 1024 + ug0, w);
  }
  if (fout) fout[(long)row * fstride + ug0 + ul] = hh;
  // NOTE: gl WAR protection comes from wg_arrive()'s __syncthreads.
}

// ---------------- VAE head, one (s,l,b) per WG ------------------------------
__device__ __forceinline__ void vae_wg(
    int bid, char* scr,
    const u16* h0f, const u16* h1f, const float* c0f, const float* c1f,
    const float* hmuW, const float* hmub, const float* hsgW, const float* hsgb,
    const float* houtW, const float* houtb,
    const float* cmuW, const float* cmub, const float* csgW, const float* csgb,
    const float* coutW, const float* coutb,
    const float* eps_h, const float* eps_c,
    float* muo, float* sgo, u16* hd0, u16* hd1, float* cd0, float* cd1)
{
  float* hrow = (float*)scr;
  float* muv  = hrow + 1024;
  float* sgv  = muv + 128;
  float* zz   = sgv + 128;
  const int tid = threadIdx.x;
  const int b = bid & 63, l = (bid >> 6) & 1, s = bid >> 7;

  if (s == 0) {
    const u16* h = (l ? h1f : h0f) + b * D_;
    for (int i = tid; i < D_; i += 512) hrow[i] = b2f(h[i]);
  } else {
    const float* c = (l ? c1f : c0f) + b * D_;
    for (int i = tid; i < D_; i += 512) hrow[i] = c[i];
  }
  __syncthreads();

  const float* muW = (s ? cmuW : hmuW) + (long)l * G_ * D_;
  const float* sgW = (s ? csgW : hsgW) + (long)l * G_ * D_;
  const float* mub = (s ? cmub : hmub) + l * G_;
  const float* sgb = (s ? csgb : hsgb) + l * G_;
  const int wv = tid >> 6, lane = tid & 63;
  for (int oi = wv; oi < 2 * G_; oi += 8) {
    const int g = (oi < G_) ? oi : oi - G_;
    const float* Wr = ((oi < G_) ? muW : sgW) + (long)g * D_;
    float d = 0.f;
    for (int j = lane; j < D_; j += 64) d += Wr[j] * hrow[j];
    for (int off = 1; off < 64; off <<= 1) d += __shfl_xor(d, off);
    if (lane == 0) {
      if (oi < G_) muv[g] = d + mub[g]; else sgv[g] = d + sgb[g];
    }
  }
  __syncthreads();
  if (tid < G_) {
    const int g = tid;
    const float mu = muv[g], sg = sgv[g];
    const float* ep = (s ? eps_c : eps_h) + ((long)l * B_ + b) * G_;
    zz[g] = mu + ep[g] * __expf(sg);
    muo[(long)bid * G_ + g] = mu;
    sgo[(long)bid * G_ + g] = sg;
  }
  __syncthreads();
  const float* oW  = (s ? coutW : houtW) + (long)l * D_ * G_;
  const float* obv = (s ? coutb : houtb) + l * D_;
  for (int i = 0; i < 2; ++i) {
    const int dd = i * 512 + tid;
    float acc = obv[dd];
    const float* Wr = oW + (long)dd * G_;
    #pragma unroll 4
    for (int g = 0; g < G_; ++g) acc += zz[g] * Wr[g];
    if (s == 0) { (l ? hd1 : hd0)[b * D_ + dd] = f2b(acc); }
    else        { (l ? cd1 : cd0)[b * D_ + dd] = acc; }
  }
  __syncthreads();
}

// ---------------- the persistent kernel -------------------------------------
__global__ __launch_bounds__(512, 1)
void persist(const u16* __restrict__ Wpe, const u16* __restrict__ Wpd,
             const float* __restrict__ bp,
             const u16* __restrict__ xb, const u16* __restrict__ xd0,
             u16* ring0, u16* ring1,
             float* ce0, float* ce1,
             u16* hd0i, u16* hd1i, float* cd0, float* cd1,
             const float* hmuW, const float* hmub, const float* hsgW, const float* hsgb,
             const float* houtW, const float* houtb,
             const float* cmuW, const float* cmub, const float* csgW, const float* csgb,
             const float* coutW, const float* coutb,
             const float* eps_h, const float* eps_c,
             float* out, float* muo, float* sgo, unsigned* bar)
{
  __shared__ __align__(16) char smem[147456 + 64]; // 128K weights + 16K + flags
  char*  wlds = smem;
  float* gl   = (float*)(smem + 131072);
  unsigned* lsf = (unsigned*)(smem + 147456);      // [0]=sig0 flag, [1]=sig1

  unsigned* gcnt = bar;
  unsigned* acnt = bar + 2048;
  unsigned* bcnt = bar + 4096;
  unsigned* ccnt = bar + 6144;
  unsigned* dcnt = bar + 8192;

  const int wg  = blockIdx.x;
  const bool isL0 = (wg < 128);
  const int wgL = wg & 127;
  const int ug0 = wgL * 8;
  const int tid = threadIdx.x;

  // ---- encoder phase (signal-driven, no grid barriers) ----
  if (tid == 0) { lsf[0] = 0; lsf[1] = 0; }        // load_weights syncs
  load_weights(Wpe + (isL0 ? 0l : (long)FD * K2) + (long)wgL * 32 * K2, wlds);
  f4 bias = *(const f4*)(bp + (isL0 ? 0 : FD) + (ug0 + (tid & 7)) * 4);
  float c_reg = 0.f;

  if (isL0) {
    for (int s = 0; s < T_; ++s) {
      cellw(xb + (long)s * BD, nullptr, 0,
            s ? (ring0 + (long)(s - 1) * BD) : nullptr,
            s ? acnt : nullptr, 8u * (unsigned)s,
            wlds, gl, lsf, (unsigned)(s + 1),
            c_reg, bias, ug0,
            ring0 + (long)s * BD, nullptr, 0);
      wg_arrive(acnt, wg);
    }
  } else {
    for (int t = 0; t < T_; ++t) {
      cellw(ring0 + (long)t * BD, acnt, 8u * (unsigned)(t + 1),
            t ? (ring1 + (long)(t - 1) * BD) : nullptr,
            t ? bcnt : nullptr, 8u * (unsigned)t,
            wlds, gl, lsf, (unsigned)(t + 1),
            c_reg, bias, ug0,
            ring1 + (long)t * BD, nullptr, 0);
      wg_arrive(bcnt, wg);
    }
  }
  // publish final c (normal stores; fenced sync follows)
  {
    const int row = tid >> 3, ul = tid & 7;
    (isL0 ? ce0 : ce1)[row * D_ + ug0 + ul] = c_reg;
  }
  fullsync(gcnt, 1, wg, true);

  // ---- VAE ----
  vae_wg(wg, (char*)gl,
         ring0 + 255l * BD, ring1 + 255l * BD, ce0, ce1,
         hmuW, hmub, hsgW, hsgb, houtW, houtb,
         cmuW, cmub, csgW, csgb, coutW, coutb,
         eps_h, eps_c, muo, sgo, hd0i, hd1i, cd0, cd1);
  fullsync(gcnt, 2, wg, true);   // also invalidates encoder-era ring lines

  // ---- decoder phase (signal-driven, 2 handoffs/step) ----
  if (tid == 0) { lsf[0] = 0; lsf[1] = 0; }        // load_weights syncs
  load_weights(Wpd + (isL0 ? 0l : (long)FD * K2) + (long)wgL * 32 * K2, wlds);
  bias = *(const f4*)(bp + 2 * FD + (isL0 ? 0 : FD) + (ug0 + (tid & 7)) * 4);
  {
    const int row = tid >> 3, ul = tid & 7;
    c_reg = (isL0 ? cd0 : cd1)[row * D_ + ug0 + ul];
  }

  if (isL0) {
    for (int t = 0; t < T_; ++t) {
      cellw(t ? (ring1 + (long)(t - 1) * BD) : xd0,
            t ? dcnt : nullptr, 8u * (unsigned)t,
            t ? (ring0 + (long)(t - 1) * BD) : hd0i,
            t ? ccnt : nullptr, 8u * (unsigned)t,
            wlds, gl, lsf, (unsigned)(t + 1),
            c_reg, bias, ug0,
            ring0 + (long)t * BD, nullptr, 0);
      wg_arrive(ccnt, wg);
    }
  } else {
    for (int t = 0; t < T_; ++t) {
      cellw(ring0 + (long)t * BD, ccnt, 8u * (unsigned)(t + 1),
            t ? (ring1 + (long)(t - 1) * BD) : hd1i,
            t ? dcnt : nullptr, 8u * (unsigned)t,
            wlds, gl, lsf, (unsigned)(t + 1),
            c_reg, bias, ug0,
            ring1 + (long)t * BD, out + (long)t * D_, (long)T_ * D_);
      wg_arrive(dcnt, wg);
    }
  }
}

// ---------------------------------------------------------------------------
// Spectral norm prepass (unchanged, verified)
// ---------------------------------------------------------------------------
__device__ __forceinline__ const float* selW(int m, const float* a, const float* b,
                                             const float* c, const float* d) {
  const float* W;
  switch (m >> 1) { case 0: W = a; break; case 1: W = b; break;
                    case 2: W = c; break; default: W = d; }
  return W + (long)(m & 1) * FD * D_;
}
__device__ __forceinline__ const float* selU(int m, const float* a, const float* b,
                                             const float* c, const float* d) {
  const float* u;
  switch (m >> 1) { case 0: u = a; break; case 1: u = b; break;
                    case 2: u = c; break; default: u = d; }
  return u + (m & 1) * FD;
}

__global__ __launch_bounds__(256)
void k_unorm(const float* euih, const float* euhh, const float* duih, const float* duhh,
             float* uinv)
{
  const int m = blockIdx.x;
  const float* u = selU(m, euih, euhh, duih, duhh);
  float s = 0.f;
  for (int i = threadIdx.x; i < FD; i += 256) { float v = u[i]; s += v * v; }
  __shared__ float red[4];
  for (int off = 1; off < 64; off <<= 1) s += __shfl_xor(s, off);
  if ((threadIdx.x & 63) == 0) red[threadIdx.x >> 6] = s;
  __syncthreads();
  if (threadIdx.x == 0)
    uinv[m] = 1.0f / (sqrtf(red[0] + red[1] + red[2] + red[3]) + 1e-12f);
}

__global__ __launch_bounds__(256)
void k_v(const float* eWih, const float* eWhh, const float* dWih, const float* dWhh,
         const float* euih, const float* euhh, const float* duih, const float* duhh,
         const float* uinv, float* v, float* vss)
{
  __shared__ float us[FD];
  __shared__ float red[4];
  const int m = blockIdx.x >> 2, cb = blockIdx.x & 3;
  const float* W = selW(m, eWih, eWhh, dWih, dWhh);
  const float* u = selU(m, euih, euhh, duih, duhh);
  for (int i = threadIdx.x; i < FD; i += 256) us[i] = u[i];
  __syncthreads();
  const int j = cb * 256 + threadIdx.x;
  float acc = 0.f;
  for (int i = 0; i < FD; ++i) acc += W[(long)i * D_ + j] * us[i];
  acc *= uinv[m];
  v[m * D_ + j] = acc;
  float s = acc * acc;
  for (int off = 1; off < 64; off <<= 1) s += __shfl_xor(s, off);
  if ((threadIdx.x & 63) == 0) red[threadIdx.x >> 6] = s;
  __syncthreads();
  if (threadIdx.x == 0) vss[blockIdx.x] = red[0] + red[1] + red[2] + red[3];
}

__global__ __launch_bounds__(256)
void k_sig(const float* eWih, const float* eWhh, const float* dWih, const float* dWhh,
           const float* v, float* sgp)
{
  __shared__ float vl[D_];
  __shared__ float red[4];
  const int m = blockIdx.x >> 6, rb = blockIdx.x & 63;
  const float* W = selW(m, eWih, eWhh, dWih, dWhh);
  for (int i = threadIdx.x; i < D_; i += 256) vl[i] = v[m * D_ + i];
  __syncthreads();
  const int wv = threadIdx.x >> 6, lane = threadIdx.x & 63;
  float ssq = 0.f;
  for (int rr = 0; rr < 16; ++rr) {
    const int r = rb * 64 + wv * 16 + rr;
    const float* Wr = W + (long)r * D_;
    float d = 0.f;
    for (int j = lane; j < D_; j += 64) d += Wr[j] * vl[j];
    for (int off = 1; off < 64; off <<= 1) d += __shfl_xor(d, off);
    ssq += d * d;
  }
  if (lane == 0) red[wv] = ssq;
  __syncthreads();
  if (threadIdx.x == 0) sgp[blockIdx.x] = red[0] + red[1] + red[2] + red[3];
}

__global__ void k_fin(const float* vss, const float* sgp, float* rsig)
{
  const int m = threadIdx.x;
  if (m < 8) {
    float vn = sqrtf(vss[m * 4] + vss[m * 4 + 1] + vss[m * 4 + 2] + vss[m * 4 + 3]);
    float s2 = 0.f;
    for (int i = 0; i < 64; ++i) s2 += sgp[m * 64 + i];
    rsig[m] = (vn + 1e-12f) / sqrtf(s2);   // 1/sigma
  }
}

__global__ __launch_bounds__(256)
void k_pack(const float* eWih, const float* eWhh, const float* dWih, const float* dWhh,
            const float* rsig, u16* Wpe, u16* Wpd)
{
  const long idx = (long)blockIdx.x * 256 + threadIdx.x;
  const int k8   = (int)(idx & 255);
  const int np   = (int)((idx >> 8) & 4095);
  const int pair = (int)(idx >> 20);
  const int l = pair & 1, ed = pair >> 1;
  const int u = np >> 2, g = np & 3;
  const int srow = g * D_ + u;
  const int k = k8 * 8;
  const float* src; float sc;
  if (k < D_) {
    const float* Wih = ed ? dWih : eWih;
    src = Wih + ((long)(l * FD + srow)) * D_ + k;
    sc  = rsig[ed ? 4 + l : l];
  } else {
    const float* Whh = ed ? dWhh : eWhh;
    src = Whh + ((long)(l * FD + srow)) * D_ + (k - D_);
    sc  = rsig[ed ? 6 + l : 2 + l];
  }
  f4 a = *(const f4*)src;
  f4 b = *(const f4*)(src + 4);
  frag8 o;
  o[0] = (short)f2b(a.x * sc); o[1] = (short)f2b(a.y * sc);
  o[2] = (short)f2b(a.z * sc); o[3] = (short)f2b(a.w * sc);
  o[4] = (short)f2b(b.x * sc); o[5] = (short)f2b(b.y * sc);
  o[6] = (short)f2b(b.z * sc); o[7] = (short)f2b(b.w * sc);
  u16* dst = (ed ? Wpd : Wpe) + ((long)(l * FD + np)) * K2 + k;
  *(frag8*)dst = o;
}

__global__ void k_packb(const float* eb, const float* db, float* bp)
{
  const int idx = blockIdx.x * 256 + threadIdx.x;   // 4*4096
  const int j = idx & 4095, pair = idx >> 12;
  const int l = pair & 1, ed = pair >> 1;
  const float* b = (ed ? db : eb) + l * FD;
  bp[pair * FD + j] = b[(j & 3) * D_ + (j >> 2)];
}

// x [B,T,D] f32 -> xb [T][B][D] bf16
__global__ __launch_bounds__(512)
void k_xb(const float* __restrict__ x, u16* __restrict__ xb)
{
  const long i8 = ((long)blockIdx.x * 512 + threadIdx.x) * 8;
  const int d  = (int)(i8 & 1023);
  const int bt = (int)(i8 >> 10);
  const int b = bt & 63, t = bt >> 6;
  const float* src = x + ((long)b * T_ + t) * D_ + d;
  f4 a = *(const f4*)src;
  f4 c = *(const f4*)(src + 4);
  frag8 o;
  o[0] = (short)f2b(a.x); o[1] = (short)f2b(a.y);
  o[2] = (short)f2b(a.z); o[3] = (short)f2b(a.w);
  o[4] = (short)f2b(c.x); o[5] = (short)f2b(c.y);
  o[6] = (short)f2b(c.z); o[7] = (short)f2b(c.w);
  *(frag8*)(xb + i8) = o;
}

__global__ __launch_bounds__(512)
void k_xd0(const float* __restrict__ initial, u16* __restrict__ xd0)
{
  const int i8 = (blockIdx.x * 512 + threadIdx.x) * 8;   // < 65536
  const int d = i8 & 1023;
  f4 a = *(const f4*)(initial + d);
  f4 c = *(const f4*)(initial + d + 4);
  frag8 o;
  o[0] = (short)f2b(a.x); o[1] = (short)f2b(a.y);
  o[2] = (short)f2b(a.z); o[3] = (short)f2b(a.w);
  o[4] = (short)f2b(c.x); o[5] = (short)f2b(c.y);
  o[6] = (short)f2b(c.z); o[7] = (short)f2b(c.w);
  *(frag8*)(xd0 + i8) = o;
}

// ---------------------------------------------------------------------------
extern "C" void kernel_launch(void* const* d_in, const int* in_sizes, int n_in,
                              void* d_out, int out_size, void* d_ws, size_t ws_size,
                              hipStream_t stream)
{
  const float* x       = (const float*)d_in[0];
  const float* initial = (const float*)d_in[1];
  const float* eWih    = (const float*)d_in[2];
  const float* eWhh    = (const float*)d_in[3];
  const float* eb      = (const float*)d_in[4];
  const float* euih    = (const float*)d_in[5];
  const float* euhh    = (const float*)d_in[6];
  const float* dWih    = (const float*)d_in[7];
  const float* dWhh    = (const float*)d_in[8];
  const float* db      = (const float*)d_in[9];
  const float* duih    = (const float*)d_in[10];
  const float* duhh    = (const float*)d_in[11];
  const float* hmuW    = (const float*)d_in[12];
  const float* hmub    = (const float*)d_in[13];
  const float* hsgW    = (const float*)d_in[14];
  const float* hsgb    = (const float*)d_in[15];
  const float* houtW   = (const float*)d_in[16];
  const float* houtb   = (const float*)d_in[17];
  const float* cmuW    = (const float*)d_in[18];
  const float* cmub    = (const float*)d_in[19];
  const float* csgW    = (const float*)d_in[20];
  const float* csgb    = (const float*)d_in[21];
  const float* coutW   = (const float*)d_in[22];
  const float* coutb   = (const float*)d_in[23];
  const float* eps_h   = (const float*)d_in[24];
  const float* eps_c   = (const float*)d_in[25];

  char* w = (char*)d_ws;
  auto alloc = [&](size_t n) -> char* {
    char* p = w; w += (n + 255) & ~(size_t)255; return p;
  };
  u16*   Wpe   = (u16*)  alloc(2l * FD * K2 * 2);       // 32 MB
  u16*   Wpd   = (u16*)  alloc(2l * FD * K2 * 2);       // 32 MB
  u16*   xb    = (u16*)  alloc((long)T_ * BD * 2);      // 32 MB
  u16*   ring0 = (u16*)  alloc((long)T_ * BD * 2);      // 32 MB
  u16*   ring1 = (u16*)  alloc((long)T_ * BD * 2);      // 32 MB
  u16*   xd0   = (u16*)  alloc((long)BD * 2);
  u16*   hd0i  = (u16*)  alloc((long)BD * 2);
  u16*   hd1i  = (u16*)  alloc((long)BD * 2);
  float* ce0   = (float*)alloc((long)BD * 4);
  float* ce1   = (float*)alloc((long)BD * 4);
  float* cd0   = (float*)alloc((long)BD * 4);
  float* cd1   = (float*)alloc((long)BD * 4);
  float* bp    = (float*)alloc(4l * FD * 4);
  float* vv    = (float*)alloc(8l * D_ * 4);
  float* uinv  = (float*)alloc(64);
  float* vss   = (float*)alloc(256);
  float* sgp   = (float*)alloc(4096);
  float* rsig  = (float*)alloc(64);
  unsigned* bar = (unsigned*)alloc(40960);   // 5 sets x 16 lines x 512B

  hipMemsetAsync(bar, 0, 40960, stream);

  k_unorm<<<8,    256, 0, stream>>>(euih, euhh, duih, duhh, uinv);
  k_v    <<<32,   256, 0, stream>>>(eWih, eWhh, dWih, dWhh, euih, euhh, duih, duhh,
                                    uinv, vv, vss);
  k_sig  <<<512,  256, 0, stream>>>(eWih, eWhh, dWih, dWhh, vv, sgp);
  k_fin  <<<1,    64,  0, stream>>>(vss, sgp, rsig);
  k_pack <<<16384,256, 0, stream>>>(eWih, eWhh, dWih, dWhh, rsig, Wpe, Wpd);
  k_packb<<<64,   256, 0, stream>>>(eb, db, bp);
  k_xb   <<<4096, 512, 0, stream>>>(x, xb);
  k_xd0  <<<16,   512, 0, stream>>>(initial, xd0);

  float* out = (float*)d_out;
  float* muo = out + (long)B_ * T_ * D_;
  float* sgo = muo + 4l * B_ * G_;

  persist<<<NWG, 512, 0, stream>>>(Wpe, Wpd, bp, xb, xd0,
                                   ring0, ring1,
                                   ce0, ce1, hd0i, hd1i, cd0, cd1,
                                   hmuW, hmub, hsgW, hsgb, houtW, houtb,
                                   cmuW, cmub, csgW, csgb, coutW, coutb,
                                   eps_h, eps_c, out, muo, sgo, bar);
}

// Round 12
// 6308.138 us; speedup vs baseline: 1.7353x; 1.0591x over previous
//
#include <hip/hip_runtime.h>

// LSTM-VAE  B=64 T=256 D=1024 L=2 G=128 — persistent kernel, signal-driven.
// Round 12: CHUNKED-K waits — producer arrival lines map to h-column chunks
// (line = wgL>>3); gated consumers wait per 512-col chunk so the straggler
// spread of the 128-producer fan-in overlaps with chunk-0 MFMA.
#define B_  64
#define T_  256
#define D_  1024
#define G_  128
#define FD  4096   // 4*D
#define K2  2048   // D (ih) + D (hh)
#define BD  65536  // B_*D_
#define NWG 256
#define CL  128    // u32 stride between counter lines (512 B)

typedef unsigned short u16;
typedef __attribute__((ext_vector_type(8))) short frag8;  // 8 bf16
typedef __attribute__((ext_vector_type(4))) float f4;
typedef __attribute__((ext_vector_type(4))) int i4;

__device__ __forceinline__ u16 f2b(float f) {
  unsigned u = __float_as_uint(f);
  u += 0x7fffu + ((u >> 16) & 1u);
  return (u16)(u >> 16);
}
__device__ __forceinline__ float b2f(u16 s) {
  return __uint_as_float(((unsigned)s) << 16);
}
__device__ __forceinline__ float sigm(float x) { return 1.0f / (1.0f + __expf(-x)); }

// write-through coherent 16B store (lands at LLC once vmcnt drains)
__device__ __forceinline__ void stcoh4(void* p, i4 w) {
  asm volatile("global_store_dwordx4 %0, %1, off sc0 sc1"
               :: "v"(p), "v"(w) : "memory");
}

// ---------------- group-signal primitives -----------------------------------
// Poller wave: lanes 0..7 poll 8 counter lines [base, base+8); when ALL >= tgt,
// lane 0 publishes val to the LDS flag.
__device__ __forceinline__ void poll8_pub(const unsigned* s, int base,
                                          unsigned tgt, unsigned* lf,
                                          unsigned val) {
  const int l = threadIdx.x & 63;
  for (;;) {
    bool ok = true;
    if (l < 8)
      ok = __hip_atomic_load(&s[(base + l) * CL], __ATOMIC_RELAXED,
                             __HIP_MEMORY_SCOPE_AGENT) >= tgt;
    if (__all(ok)) break;
    __builtin_amdgcn_s_sleep(1);
  }
  if (l == 0)
    __hip_atomic_store(lf, val, __ATOMIC_RELAXED, __HIP_MEMORY_SCOPE_WORKGROUP);
  asm volatile("" ::: "memory");
}

// Sibling waves: spin on the LDS flag (no fabric traffic).
__device__ __forceinline__ void lds_wait(const unsigned* lf, unsigned seq) {
  while (__hip_atomic_load(lf, __ATOMIC_RELAXED,
                           __HIP_MEMORY_SCOPE_WORKGROUP) < seq)
    __builtin_amdgcn_s_sleep(1);
  asm volatile("" ::: "memory");
}

// arrive: drain this WG's (coherent) stores, then one atomic add to `line`.
__device__ __forceinline__ void wg_arrive(unsigned* cnt, int line) {
  asm volatile("s_waitcnt vmcnt(0)" ::: "memory");
  __syncthreads();
  if (threadIdx.x == 0)
    __hip_atomic_fetch_add(&cnt[line * CL], 1u, __ATOMIC_RELAXED,
                           __HIP_MEMORY_SCOPE_AGENT);
}

// full-wave poll for phase-edge syncs (rare; contention irrelevant there)
__device__ __forceinline__ void wave_wait16(const unsigned* cnt, unsigned tgt) {
  const int l = threadIdx.x & 63;
  if (l < 16) {
    while (__hip_atomic_load(&cnt[l * CL], __ATOMIC_RELAXED,
                             __HIP_MEMORY_SCOPE_AGENT) < tgt)
      __builtin_amdgcn_s_sleep(2);
  }
  asm volatile("" ::: "memory");
}

// full-grid sync (phase edges only); fenced = release/acquire cache ops
__device__ __forceinline__ void fullsync(unsigned* g, unsigned ep, int wg,
                                         bool fenced) {
  if (fenced) __builtin_amdgcn_fence(__ATOMIC_RELEASE, "agent");
  wg_arrive(g, wg & 15);
  wave_wait16(g, ep * 16u);
  __syncthreads();
  if (fenced) {
    __builtin_amdgcn_fence(__ATOMIC_ACQUIRE, "agent");
    __syncthreads();
  }
}

// ---------------- weight slice load: 32 rows x 2048 bf16, XOR-swizzled ------
__device__ __forceinline__ void load_weights(const u16* __restrict__ Wg, char* wlds) {
  const int t  = threadIdx.x;
  const int r  = t >> 4;           // 0..31
  const int c0 = t & 15;
  const char* src = (const char*)(Wg + (long)r * K2);
  char* dstrow = wlds + (r << 12);
  const int swz = (r & 7) << 4;
  #pragma unroll
  for (int i = 0; i < 16; ++i) {
    const int cb = (c0 + (i << 4)) << 4;      // chunk byte offset
    frag8 v = *(const frag8*)(src + cb);
    *(frag8*)(dstrow + (cb ^ swz)) = v;
  }
  __syncthreads();
}

// ---------------- one LSTM cell, chunked-K dependency waits -----------------
// A0 (k<1024) gated by (c0p,t0); A1 (k>=1024) by (c1p,t1). null = ready.
// Wave 0 polls sig0, wave 4 polls sig1; siblings spin on LDS flags.
// Gated waits are 2-chunk: lines 0-7 gate kk<16 (cols [0,512)); lines 8-15
// gate kk>=16. Flag values 2*seq and 2*seq+1 (monotonic).
__device__ __forceinline__ void cellw(
    const u16* __restrict__ A0, const unsigned* c0p, unsigned t0,
    const u16* __restrict__ A1, const unsigned* c1p, unsigned t1,
    const char* wlds, float* gl, unsigned* lsf, unsigned seq,
    float& c_reg, const f4& bias, int ug0,
    u16* __restrict__ hout, float* __restrict__ fout, long fstride)
{
  const int tid = threadIdx.x;
  const int lane = tid & 63, wv = tid >> 6;
  const int mt = wv & 3, kh = wv >> 2;
  const int l15 = lane & 15, lgr = lane >> 4;

  f4 acc0 = (f4){0.f,0.f,0.f,0.f}, acc1 = (f4){0.f,0.f,0.f,0.f};
  const u16* Ab = kh ? A1 : A0;
  const unsigned* cp = kh ? c1p : c0p;
  const unsigned tg  = kh ? t1 : t0;
  unsigned* lf = lsf + kh;
  if (Ab) {
    const u16* ap = Ab + (mt * 16 + l15) * 1024 + lgr * 8;
    const int kbyte0 = (kh << 11) + (lgr << 4);
    const int swz = (l15 & 7) << 4;
    const char* w0r = wlds + ((long)l15 << 12);
    const char* w1r = wlds + ((long)(16 + l15) << 12);
    if (cp) {
      if (mt == 0) {
        poll8_pub(cp, 0, tg, lf, 2u * seq);        // chunk 0 ready
        poll8_pub(cp, 8, tg, lf, 2u * seq + 1u);   // chunk 1 ready
      } else {
        lds_wait(lf, 2u * seq);
      }
    }
    #pragma unroll 8
    for (int kk = 0; kk < 16; ++kk) {
      frag8 af = *(const frag8*)(ap + kk * 32);
      const int kb = (kbyte0 + (kk << 6)) ^ swz;
      frag8 b0 = *(const frag8*)(w0r + kb);
      frag8 b1 = *(const frag8*)(w1r + kb);
      acc0 = __builtin_amdgcn_mfma_f32_16x16x32_bf16(af, b0, acc0, 0, 0, 0);
      acc1 = __builtin_amdgcn_mfma_f32_16x16x32_bf16(af, b1, acc1, 0, 0, 0);
    }
    if (cp && mt != 0) lds_wait(lf, 2u * seq + 1u);
    #pragma unroll 8
    for (int kk = 16; kk < 32; ++kk) {
      frag8 af = *(const frag8*)(ap + kk * 32);
      const int kb = (kbyte0 + (kk << 6)) ^ swz;
      frag8 b0 = *(const frag8*)(w0r + kb);
      frag8 b1 = *(const frag8*)(w1r + kb);
      acc0 = __builtin_amdgcn_mfma_f32_16x16x32_bf16(af, b0, acc0, 0, 0, 0);
      acc1 = __builtin_amdgcn_mfma_f32_16x16x32_bf16(af, b1, acc1, 0, 0, 0);
    }
  }
  float* g = gl + kh * (64 * 32);
  const int orow = mt * 16 + lgr * 4;
  #pragma unroll
  for (int r = 0; r < 4; ++r) {
    g[(orow + r) * 32 + l15]      = acc0[r];
    g[(orow + r) * 32 + 16 + l15] = acc1[r];
  }
  __syncthreads();

  const int row = tid >> 3, ul = tid & 7;
  f4 p0 = *(const f4*)(gl + row * 32 + ul * 4);
  f4 p1 = *(const f4*)(gl + 64 * 32 + row * 32 + ul * 4);
  float iv = p0.x + p1.x + bias.x;
  float fv = p0.y + p1.y + bias.y;
  float gv = p0.z + p1.z + bias.z;
  float ov = p0.w + p1.w + bias.w;
  float cn = sigm(fv) * c_reg + sigm(iv) * tanhf(gv);
  float hh = sigm(ov) * tanhf(cn);
  c_reg = cn;
  // pack the 8-unit row (16B) with 4 shfl_xor; one dwordx4 per row (ul==0)
  unsigned hv = (unsigned)f2b(hh);
  unsigned a  = hv | (__shfl_xor(hv, 1) << 16);   // (u, u+1) at even ul
  unsigned b  = __shfl_xor(a, 2);                 // (u2,u3) at ul0
  unsigned c2 = __shfl_xor(a, 4);                 // (u4,u5) at ul0
  unsigned d2 = __shfl_xor(b, 4);                 // (u6,u7) at ul0
  if (ul == 0) {
    i4 w; w.x = (int)a; w.y = (int)b; w.z = (int)c2; w.w = (int)d2;
    stcoh4(hout + row * 1024 + ug0, w);
  }
  if (fout) fout[(long)row * fstride + ug0 + ul] = hh;
  // NOTE: gl WAR protection comes from wg_arrive()'s __syncthreads.
}

// ---------------- VAE head, one (s,l,b) per WG ------------------------------
__device__ __forceinline__ void vae_wg(
    int bid, char* scr,
    const u16* h0f, const u16* h1f, const float* c0f, const float* c1f,
    const float* hmuW, const float* hmub, const float* hsgW, const float* hsgb,
    const float* houtW, const float* houtb,
    const float* cmuW, const float* cmub, const float* csgW, const float* csgb,
    const float* coutW, const float* coutb,
    const float* eps_h, const float* eps_c,
    float* muo, float* sgo, u16* hd0, u16* hd1, float* cd0, float* cd1)
{
  float* hrow = (float*)scr;
  float* muv  = hrow + 1024;
  float* sgv  = muv + 128;
  float* zz   = sgv + 128;
  const int tid = threadIdx.x;
  const int b = bid & 63, l = (bid >> 6) & 1, s = bid >> 7;

  if (s == 0) {
    const u16* h = (l ? h1f : h0f) + b * D_;
    for (int i = tid; i < D_; i += 512) hrow[i] = b2f(h[i]);
  } else {
    const float* c = (l ? c1f : c0f) + b * D_;
    for (int i = tid; i < D_; i += 512) hrow[i] = c[i];
  }
  __syncthreads();

  const float* muW = (s ? cmuW : hmuW) + (long)l * G_ * D_;
  const float* sgW = (s ? csgW : hsgW) + (long)l * G_ * D_;
  const float* mub = (s ? cmub : hmub) + l * G_;
  const float* sgb = (s ? csgb : hsgb) + l * G_;
  const int wv = tid >> 6, lane = tid & 63;
  for (int oi = wv; oi < 2 * G_; oi += 8) {
    const int g = (oi < G_) ? oi : oi - G_;
    const float* Wr = ((oi < G_) ? muW : sgW) + (long)g * D_;
    float d = 0.f;
    for (int j = lane; j < D_; j += 64) d += Wr[j] * hrow[j];
    for (int off = 1; off < 64; off <<= 1) d += __shfl_xor(d, off);
    if (lane == 0) {
      if (oi < G_) muv[g] = d + mub[g]; else sgv[g] = d + sgb[g];
    }
  }
  __syncthreads();
  if (tid < G_) {
    const int g = tid;
    const float mu = muv[g], sg = sgv[g];
    const float* ep = (s ? eps_c : eps_h) + ((long)l * B_ + b) * G_;
    zz[g] = mu + ep[g] * __expf(sg);
    muo[(long)bid * G_ + g] = mu;
    sgo[(long)bid * G_ + g] = sg;
  }
  __syncthreads();
  const float* oW  = (s ? coutW : houtW) + (long)l * D_ * G_;
  const float* obv = (s ? coutb : houtb) + l * D_;
  for (int i = 0; i < 2; ++i) {
    const int dd = i * 512 + tid;
    float acc = obv[dd];
    const float* Wr = oW + (long)dd * G_;
    #pragma unroll 4
    for (int g = 0; g < G_; ++g) acc += zz[g] * Wr[g];
    if (s == 0) { (l ? hd1 : hd0)[b * D_ + dd] = f2b(acc); }
    else        { (l ? cd1 : cd0)[b * D_ + dd] = acc; }
  }
  __syncthreads();
}

// ---------------- the persistent kernel -------------------------------------
__global__ __launch_bounds__(512, 1)
void persist(const u16* __restrict__ Wpe, const u16* __restrict__ Wpd,
             const float* __restrict__ bp,
             const u16* __restrict__ xb, const u16* __restrict__ xd0,
             u16* ring0, u16* ring1,
             float* ce0, float* ce1,
             u16* hd0i, u16* hd1i, float* cd0, float* cd1,
             const float* hmuW, const float* hmub, const float* hsgW, const float* hsgb,
             const float* houtW, const float* houtb,
             const float* cmuW, const float* cmub, const float* csgW, const float* csgb,
             const float* coutW, const float* coutb,
             const float* eps_h, const float* eps_c,
             float* out, float* muo, float* sgo, unsigned* bar)
{
  __shared__ __align__(16) char smem[147456 + 64]; // 128K weights + 16K + flags
  char*  wlds = smem;
  float* gl   = (float*)(smem + 131072);
  unsigned* lsf = (unsigned*)(smem + 147456);      // [0]=sig0 flag, [1]=sig1

  unsigned* gcnt = bar;
  unsigned* acnt = bar + 2048;
  unsigned* bcnt = bar + 4096;
  unsigned* ccnt = bar + 6144;
  unsigned* dcnt = bar + 8192;

  const int wg  = blockIdx.x;
  const bool isL0 = (wg < 128);
  const int wgL = wg & 127;
  const int ug0 = wgL * 8;
  const int tid = threadIdx.x;
  const int aline = wgL >> 3;       // arrival line = column chunk of this WG

  // ---- encoder phase (signal-driven, no grid barriers) ----
  if (tid == 0) { lsf[0] = 0; lsf[1] = 0; }        // load_weights syncs
  load_weights(Wpe + (isL0 ? 0l : (long)FD * K2) + (long)wgL * 32 * K2, wlds);
  f4 bias = *(const f4*)(bp + (isL0 ? 0 : FD) + (ug0 + (tid & 7)) * 4);
  float c_reg = 0.f;

  if (isL0) {
    for (int s = 0; s < T_; ++s) {
      cellw(xb + (long)s * BD, nullptr, 0,
            s ? (ring0 + (long)(s - 1) * BD) : nullptr,
            s ? acnt : nullptr, 8u * (unsigned)s,
            wlds, gl, lsf, (unsigned)(s + 1),
            c_reg, bias, ug0,
            ring0 + (long)s * BD, nullptr, 0);
      wg_arrive(acnt, aline);
    }
  } else {
    for (int t = 0; t < T_; ++t) {
      cellw(ring0 + (long)t * BD, acnt, 8u * (unsigned)(t + 1),
            t ? (ring1 + (long)(t - 1) * BD) : nullptr,
            t ? bcnt : nullptr, 8u * (unsigned)t,
            wlds, gl, lsf, (unsigned)(t + 1),
            c_reg, bias, ug0,
            ring1 + (long)t * BD, nullptr, 0);
      wg_arrive(bcnt, aline);
    }
  }
  // publish final c (normal stores; fenced sync follows)
  {
    const int row = tid >> 3, ul = tid & 7;
    (isL0 ? ce0 : ce1)[row * D_ + ug0 + ul] = c_reg;
  }
  fullsync(gcnt, 1, wg, true);

  // ---- VAE ----
  vae_wg(wg, (char*)gl,
         ring0 + 255l * BD, ring1 + 255l * BD, ce0, ce1,
         hmuW, hmub, hsgW, hsgb, houtW, houtb,
         cmuW, cmub, csgW, csgb, coutW, coutb,
         eps_h, eps_c, muo, sgo, hd0i, hd1i, cd0, cd1);
  fullsync(gcnt, 2, wg, true);   // also invalidates encoder-era ring lines

  // ---- decoder phase (signal-driven, 2 handoffs/step) ----
  if (tid == 0) { lsf[0] = 0; lsf[1] = 0; }        // load_weights syncs
  load_weights(Wpd + (isL0 ? 0l : (long)FD * K2) + (long)wgL * 32 * K2, wlds);
  bias = *(const f4*)(bp + 2 * FD + (isL0 ? 0 : FD) + (ug0 + (tid & 7)) * 4);
  {
    const int row = tid >> 3, ul = tid & 7;
    c_reg = (isL0 ? cd0 : cd1)[row * D_ + ug0 + ul];
  }

  if (isL0) {
    for (int t = 0; t < T_; ++t) {
      cellw(t ? (ring1 + (long)(t - 1) * BD) : xd0,
            t ? dcnt : nullptr, 8u * (unsigned)t,
            t ? (ring0 + (long)(t - 1) * BD) : hd0i,
            t ? ccnt : nullptr, 8u * (unsigned)t,
            wlds, gl, lsf, (unsigned)(t + 1),
            c_reg, bias, ug0,
            ring0 + (long)t * BD, nullptr, 0);
      wg_arrive(ccnt, aline);
    }
  } else {
    for (int t = 0; t < T_; ++t) {
      cellw(ring0 + (long)t * BD, ccnt, 8u * (unsigned)(t + 1),
            t ? (ring1 + (long)(t - 1) * BD) : hd1i,
            t ? dcnt : nullptr, 8u * (unsigned)t,
            wlds, gl, lsf, (unsigned)(t + 1),
            c_reg, bias, ug0,
            ring1 + (long)t * BD, out + (long)t * D_, (long)T_ * D_);
      wg_arrive(dcnt, aline);
    }
  }
}

// ---------------------------------------------------------------------------
// Spectral norm prepass (unchanged, verified)
// ---------------------------------------------------------------------------
__device__ __forceinline__ const float* selW(int m, const float* a, const float* b,
                                             const float* c, const float* d) {
  const float* W;
  switch (m >> 1) { case 0: W = a; break; case 1: W = b; break;
                    case 2: W = c; break; default: W = d; }
  return W + (long)(m & 1) * FD * D_;
}
__device__ __forceinline__ const float* selU(int m, const float* a, const float* b,
                                             const float* c, const float* d) {
  const float* u;
  switch (m >> 1) { case 0: u = a; break; case 1: u = b; break;
                    case 2: u = c; break; default: u = d; }
  return u + (m & 1) * FD;
}

__global__ __launch_bounds__(256)
void k_unorm(const float* euih, const float* euhh, const float* duih, const float* duhh,
             float* uinv)
{
  const int m = blockIdx.x;
  const float* u = selU(m, euih, euhh, duih, duhh);
  float s = 0.f;
  for (int i = threadIdx.x; i < FD; i += 256) { float v = u[i]; s += v * v; }
  __shared__ float red[4];
  for (int off = 1; off < 64; off <<= 1) s += __shfl_xor(s, off);
  if ((threadIdx.x & 63) == 0) red[threadIdx.x >> 6] = s;
  __syncthreads();
  if (threadIdx.x == 0)
    uinv[m] = 1.0f / (sqrtf(red[0] + red[1] + red[2] + red[3]) + 1e-12f);
}

__global__ __launch_bounds__(256)
void k_v(const float* eWih, const float* eWhh, const float* dWih, const float* dWhh,
         const float* euih, const float* euhh, const float* duih, const float* duhh,
         const float* uinv, float* v, float* vss)
{
  __shared__ float us[FD];
  __shared__ float red[4];
  const int m = blockIdx.x >> 2, cb = blockIdx.x & 3;
  const float* W = selW(m, eWih, eWhh, dWih, dWhh);
  const float* u = selU(m, euih, euhh, duih, duhh);
  for (int i = threadIdx.x; i < FD; i += 256) us[i] = u[i];
  __syncthreads();
  const int j = cb * 256 + threadIdx.x;
  float acc = 0.f;
  for (int i = 0; i < FD; ++i) acc += W[(long)i * D_ + j] * us[i];
  acc *= uinv[m];
  v[m * D_ + j] = acc;
  float s = acc * acc;
  for (int off = 1; off < 64; off <<= 1) s += __shfl_xor(s, off);
  if ((threadIdx.x & 63) == 0) red[threadIdx.x >> 6] = s;
  __syncthreads();
  if (threadIdx.x == 0) vss[blockIdx.x] = red[0] + red[1] + red[2] + red[3];
}

__global__ __launch_bounds__(256)
void k_sig(const float* eWih, const float* eWhh, const float* dWih, const float* dWhh,
           const float* v, float* sgp)
{
  __shared__ float vl[D_];
  __shared__ float red[4];
  const int m = blockIdx.x >> 6, rb = blockIdx.x & 63;
  const float* W = selW(m, eWih, eWhh, dWih, dWhh);
  for (int i = threadIdx.x; i < D_; i += 256) vl[i] = v[m * D_ + i];
  __syncthreads();
  const int wv = threadIdx.x >> 6, lane = threadIdx.x & 63;
  float ssq = 0.f;
  for (int rr = 0; rr < 16; ++rr) {
    const int r = rb * 64 + wv * 16 + rr;
    const float* Wr = W + (long)r * D_;
    float d = 0.f;
    for (int j = lane; j < D_; j += 64) d += Wr[j] * vl[j];
    for (int off = 1; off < 64; off <<= 1) d += __shfl_xor(d, off);
    ssq += d * d;
  }
  if (lane == 0) red[wv] = ssq;
  __syncthreads();
  if (threadIdx.x == 0) sgp[blockIdx.x] = red[0] + red[1] + red[2] + red[3];
}

__global__ void k_fin(const float* vss, const float* sgp, float* rsig)
{
  const int m = threadIdx.x;
  if (m < 8) {
    float vn = sqrtf(vss[m * 4] + vss[m * 4 + 1] + vss[m * 4 + 2] + vss[m * 4 + 3]);
    float s2 = 0.f;
    for (int i = 0; i < 64; ++i) s2 += sgp[m * 64 + i];
    rsig[m] = (vn + 1e-12f) / sqrtf(s2);   // 1/sigma
  }
}

__global__ __launch_bounds__(256)
void k_pack(const float* eWih, const float* eWhh, const float* dWih, const float* dWhh,
            const float* rsig, u16* Wpe, u16* Wpd)
{
  const long idx = (long)blockIdx.x * 256 + threadIdx.x;
  const int k8   = (int)(idx & 255);
  const int np   = (int)((idx >> 8) & 4095);
  const int pair = (int)(idx >> 20);
  const int l = pair & 1, ed = pair >> 1;
  const int u = np >> 2, g = np & 3;
  const int srow = g * D_ + u;
  const int k = k8 * 8;
  const float* src; float sc;
  if (k < D_) {
    const float* Wih = ed ? dWih : eWih;
    src = Wih + ((long)(l * FD + srow)) * D_ + k;
    sc  = rsig[ed ? 4 + l : l];
  } else {
    const float* Whh = ed ? dWhh : eWhh;
    src = Whh + ((long)(l * FD + srow)) * D_ + (k - D_);
    sc  = rsig[ed ? 6 + l : 2 + l];
  }
  f4 a = *(const f4*)src;
  f4 b = *(const f4*)(src + 4);
  frag8 o;
  o[0] = (short)f2b(a.x * sc); o[1] = (short)f2b(a.y * sc);
  o[2] = (short)f2b(a.z * sc); o[3] = (short)f2b(a.w * sc);
  o[4] = (short)f2b(b.x * sc); o[5] = (short)f2b(b.y * sc);
  o[6] = (short)f2b(b.z * sc); o[7] = (short)f2b(b.w * sc);
  u16* dst = (ed ? Wpd : Wpe) + ((long)(l * FD + np)) * K2 + k;
  *(frag8*)dst = o;
}

__global__ void k_packb(const float* eb, const float* db, float* bp)
{
  const int idx = blockIdx.x * 256 + threadIdx.x;   // 4*4096
  const int j = idx & 4095, pair = idx >> 12;
  const int l = pair & 1, ed = pair >> 1;
  const float* b = (ed ? db : eb) + l * FD;
  bp[pair * FD + j] = b[(j & 3) * D_ + (j >> 2)];
}

// x [B,T,D] f32 -> xb [T][B][D] bf16
__global__ __launch_bounds__(512)
void k_xb(const float* __restrict__ x, u16* __restrict__ xb)
{
  const long i8 = ((long)blockIdx.x * 512 + threadIdx.x) * 8;
  const int d  = (int)(i8 & 1023);
  const int bt = (int)(i8 >> 10);
  const int b = bt & 63, t = bt >> 6;
  const float* src = x + ((long)b * T_ + t) * D_ + d;
  f4 a = *(const f4*)src;
  f4 c = *(const f4*)(src + 4);
  frag8 o;
  o[0] = (short)f2b(a.x); o[1] = (short)f2b(a.y);
  o[2] = (short)f2b(a.z); o[3] = (short)f2b(a.w);
  o[4] = (short)f2b(c.x); o[5] = (short)f2b(c.y);
  o[6] = (short)f2b(c.z); o[7] = (short)f2b(c.w);
  *(frag8*)(xb + i8) = o;
}

__global__ __launch_bounds__(512)
void k_xd0(const float* __restrict__ initial, u16* __restrict__ xd0)
{
  const int i8 = (blockIdx.x * 512 + threadIdx.x) * 8;   // < 65536
  const int d = i8 & 1023;
  f4 a = *(const f4*)(initial + d);
  f4 c = *(const f4*)(initial + d + 4);
  frag8 o;
  o[0] = (short)f2b(a.x); o[1] = (short)f2b(a.y);
  o[2] = (short)f2b(a.z); o[3] = (short)f2b(a.w);
  o[4] = (short)f2b(c.x); o[5] = (short)f2b(c.y);
  o[6] = (short)f2b(c.z); o[7] = (short)f2b(c.w);
  *(frag8*)(xd0 + i8) = o;
}

// ---------------------------------------------------------------------------
extern "C" void kernel_launch(void* const* d_in, const int* in_sizes, int n_in,
                              void* d_out, int out_size, void* d_ws, size_t ws_size,
                              hipStream_t stream)
{
  const float* x       = (const float*)d_in[0];
  const float* initial = (const float*)d_in[1];
  const float* eWih    = (const float*)d_in[2];
  const float* eWhh    = (const float*)d_in[3];
  const float* eb      = (const float*)d_in[4];
  const float* euih    = (const float*)d_in[5];
  const float* euhh    = (const float*)d_in[6];
  const float* dWih    = (const float*)d_in[7];
  const float* dWhh    = (const float*)d_in[8];
  const float* db      = (const float*)d_in[9];
  const float* duih    = (const float*)d_in[10];
  const float* duhh    = (const float*)d_in[11];
  const float* hmuW    = (const float*)d_in[12];
  const float* hmub    = (const float*)d_in[13];
  const float* hsgW    = (const float*)d_in[14];
  const float* hsgb    = (const float*)d_in[15];
  const float* houtW   = (const float*)d_in[16];
  const float* houtb   = (const float*)d_in[17];
  const float* cmuW    = (const float*)d_in[18];
  const float* cmub    = (const float*)d_in[19];
  const float* csgW    = (const float*)d_in[20];
  const float* csgb    = (const float*)d_in[21];
  const float* coutW   = (const float*)d_in[22];
  const float* coutb   = (const float*)d_in[23];
  const float* eps_h   = (const float*)d_in[24];
  const float* eps_c   = (const float*)d_in[25];

  char* w = (char*)d_ws;
  auto alloc = [&](size_t n) -> char* {
    char* p = w; w += (n + 255) & ~(size_t)255; return p;
  };
  u16*   Wpe   = (u16*)  alloc(2l * FD * K2 * 2);       // 32 MB
  u16*   Wpd   = (u16*)  alloc(2l * FD * K2 * 2);       // 32 MB
  u16*   xb    = (u16*)  alloc((long)T_ * BD * 2);      // 32 MB
  u16*   ring0 = (u16*)  alloc((long)T_ * BD * 2);      // 32 MB
  u16*   ring1 = (u16*)  alloc((long)T_ * BD * 2);      // 32 MB
  u16*   xd0   = (u16*)  alloc((long)BD * 2);
  u16*   hd0i  = (u16*)  alloc((long)BD * 2);
  u16*   hd1i  = (u16*)  alloc((long)BD * 2);
  float* ce0   = (float*)alloc((long)BD * 4);
  float* ce1   = (float*)alloc((long)BD * 4);
  float* cd0   = (float*)alloc((long)BD * 4);
  float* cd1   = (float*)alloc((long)BD * 4);
  float* bp    = (float*)alloc(4l * FD * 4);
  float* vv    = (float*)alloc(8l * D_ * 4);
  float* uinv  = (float*)alloc(64);
  float* vss   = (float*)alloc(256);
  float* sgp   = (float*)alloc(4096);
  float* rsig  = (float*)alloc(64);
  unsigned* bar = (unsigned*)alloc(40960);   // 5 sets x 16 lines x 512B

  hipMemsetAsync(bar, 0, 40960, stream);

  k_unorm<<<8,    256, 0, stream>>>(euih, euhh, duih, duhh, uinv);
  k_v    <<<32,   256, 0, stream>>>(eWih, eWhh, dWih, dWhh, euih, euhh, duih, duhh,
                                    uinv, vv, vss);
  k_sig  <<<512,  256, 0, stream>>>(eWih, eWhh, dWih, dWhh, vv, sgp);
  k_fin  <<<1,    64,  0, stream>>>(vss, sgp, rsig);
  k_pack <<<16384,256, 0, stream>>>(eWih, eWhh, dWih, dWhh, rsig, Wpe, Wpd);
  k_packb<<<64,   256, 0, stream>>>(eb, db, bp);
  k_xb   <<<4096, 512, 0, stream>>>(x, xb);
  k_xd0  <<<16,   512, 0, stream>>>(initial, xd0);

  float* out = (float*)d_out;
  float* muo = out + (long)B_ * T_ * D_;
  float* sgo = muo + 4l * B_ * G_;

  persist<<<NWG, 512, 0, stream>>>(Wpe, Wpd, bp, xb, xd0,
                                   ring0, ring1,
                                   ce0, ce1, hd0i, hd1i, cd0, cd1,
                                   hmuW, hmub, hsgW, hsgb, houtW, houtb,
                                   cmuW, cmub, csgW, csgb, coutW, coutb,
                                   eps_h, eps_c, out, muo, sgo, bar);
}

// Round 13
// 5913.506 us; speedup vs baseline: 1.8511x; 1.0667x over previous
//
#include <hip/hip_runtime.h>

// LSTM-VAE  B=64 T=256 D=1024 L=2 G=128 — persistent kernel, signal-driven.
// Round 13: PERMUTED h layout hP[m=unit>>3][row][8] -> each producer WG writes
// 1KB contiguous (16 full lines, no partial-line RMW at LLC); 4-chunk gated
// waits with poller interleaving poll/compute.
#define B_  64
#define T_  256
#define D_  1024
#define G_  128
#define FD  4096   // 4*D
#define K2  2048   // D (ih) + D (hh)
#define BD  65536  // B_*D_
#define NWG 256
#define CL  128    // u32 stride between counter lines (512 B)

typedef unsigned short u16;
typedef __attribute__((ext_vector_type(8))) short frag8;  // 8 bf16
typedef __attribute__((ext_vector_type(4))) float f4;
typedef __attribute__((ext_vector_type(4))) int i4;

__device__ __forceinline__ u16 f2b(float f) {
  unsigned u = __float_as_uint(f);
  u += 0x7fffu + ((u >> 16) & 1u);
  return (u16)(u >> 16);
}
__device__ __forceinline__ float b2f(u16 s) {
  return __uint_as_float(((unsigned)s) << 16);
}
__device__ __forceinline__ float sigm(float x) { return 1.0f / (1.0f + __expf(-x)); }

// write-through coherent 16B store (lands at LLC once vmcnt drains)
__device__ __forceinline__ void stcoh4(void* p, i4 w) {
  asm volatile("global_store_dwordx4 %0, %1, off sc0 sc1"
               :: "v"(p), "v"(w) : "memory");
}

// ---------------- group-signal primitives -----------------------------------
// Poller wave: lanes 0..3 poll 4 counter lines [base, base+4); when ALL >= tgt,
// lane 0 publishes val to the LDS flag.
__device__ __forceinline__ void poll4_pub(const unsigned* s, int base,
                                          unsigned tgt, unsigned* lf,
                                          unsigned val) {
  const int l = threadIdx.x & 63;
  for (;;) {
    bool ok = true;
    if (l < 4)
      ok = __hip_atomic_load(&s[(base + l) * CL], __ATOMIC_RELAXED,
                             __HIP_MEMORY_SCOPE_AGENT) >= tgt;
    if (__all(ok)) break;
    __builtin_amdgcn_s_sleep(1);
  }
  if (l == 0)
    __hip_atomic_store(lf, val, __ATOMIC_RELAXED, __HIP_MEMORY_SCOPE_WORKGROUP);
  asm volatile("" ::: "memory");
}

// Sibling waves: spin on the LDS flag (no fabric traffic).
__device__ __forceinline__ void lds_wait(const unsigned* lf, unsigned seq) {
  while (__hip_atomic_load(lf, __ATOMIC_RELAXED,
                           __HIP_MEMORY_SCOPE_WORKGROUP) < seq)
    __builtin_amdgcn_s_sleep(1);
  asm volatile("" ::: "memory");
}

// arrive: drain this WG's (coherent) stores, then one atomic add to `line`.
__device__ __forceinline__ void wg_arrive(unsigned* cnt, int line) {
  asm volatile("s_waitcnt vmcnt(0)" ::: "memory");
  __syncthreads();
  if (threadIdx.x == 0)
    __hip_atomic_fetch_add(&cnt[line * CL], 1u, __ATOMIC_RELAXED,
                           __HIP_MEMORY_SCOPE_AGENT);
}

// full-wave poll for phase-edge syncs (rare; contention irrelevant there)
__device__ __forceinline__ void wave_wait16(const unsigned* cnt, unsigned tgt) {
  const int l = threadIdx.x & 63;
  if (l < 16) {
    while (__hip_atomic_load(&cnt[l * CL], __ATOMIC_RELAXED,
                             __HIP_MEMORY_SCOPE_AGENT) < tgt)
      __builtin_amdgcn_s_sleep(2);
  }
  asm volatile("" ::: "memory");
}

// full-grid sync (phase edges only); fenced = release/acquire cache ops
__device__ __forceinline__ void fullsync(unsigned* g, unsigned ep, int wg,
                                         bool fenced) {
  if (fenced) __builtin_amdgcn_fence(__ATOMIC_RELEASE, "agent");
  wg_arrive(g, wg & 15);
  wave_wait16(g, ep * 16u);
  __syncthreads();
  if (fenced) {
    __builtin_amdgcn_fence(__ATOMIC_ACQUIRE, "agent");
    __syncthreads();
  }
}

// ---------------- weight slice load: 32 rows x 2048 bf16, XOR-swizzled ------
__device__ __forceinline__ void load_weights(const u16* __restrict__ Wg, char* wlds) {
  const int t  = threadIdx.x;
  const int r  = t >> 4;           // 0..31
  const int c0 = t & 15;
  const char* src = (const char*)(Wg + (long)r * K2);
  char* dstrow = wlds + (r << 12);
  const int swz = (r & 7) << 4;
  #pragma unroll
  for (int i = 0; i < 16; ++i) {
    const int cb = (c0 + (i << 4)) << 4;      // chunk byte offset
    frag8 v = *(const frag8*)(src + cb);
    *(frag8*)(dstrow + (cb ^ swz)) = v;
  }
  __syncthreads();
}

// ---------------- one LSTM cell, 4-chunk dependency waits -------------------
// A operands are PERMUTED: A[(m*64+row)*8 + u] = h[row][m*8+u], m = 0..127.
// A0 gated by (c0p,t0); A1 by (c1p,t1). null cp = ready.
// Chunk c: producer lines [4c,4c+4) gate kk in [8c, 8c+8).
// Poller waves (mt==0) interleave poll-chunk / compute-chunk.
__device__ __forceinline__ void cellw(
    const u16* __restrict__ A0, const unsigned* c0p, unsigned t0,
    const u16* __restrict__ A1, const unsigned* c1p, unsigned t1,
    const char* wlds, float* gl, unsigned* lsf, unsigned seq,
    float& c_reg, const f4& bias, int ug0,
    u16* __restrict__ hout, float* __restrict__ fout, long fstride)
{
  const int tid = threadIdx.x;
  const int lane = tid & 63, wv = tid >> 6;
  const int mt = wv & 3, kh = wv >> 2;
  const int l15 = lane & 15, lgr = lane >> 4;

  f4 acc0 = (f4){0.f,0.f,0.f,0.f}, acc1 = (f4){0.f,0.f,0.f,0.f};
  const u16* Ab = kh ? A1 : A0;
  const unsigned* cp = kh ? c1p : c0p;
  const unsigned tg  = kh ? t1 : t0;
  unsigned* lf = lsf + kh;
  if (Ab) {
    const u16* apb = Ab + (lgr * 64 + mt * 16 + l15) * 8;   // permuted base
    const int kbyte0 = (kh << 11) + (lgr << 4);
    const int swz = (l15 & 7) << 4;
    const char* w0r = wlds + ((long)l15 << 12);
    const char* w1r = wlds + ((long)(16 + l15) << 12);
    if (cp) {
      const unsigned fb = 4u * (seq - 1u);
      #pragma unroll
      for (int cc = 0; cc < 4; ++cc) {
        if (mt == 0) poll4_pub(cp, cc * 4, tg, lf, fb + (unsigned)cc + 1u);
        else         lds_wait(lf, fb + (unsigned)cc + 1u);
        #pragma unroll
        for (int kk = cc * 8; kk < cc * 8 + 8; ++kk) {
          frag8 af = *(const frag8*)(apb + kk * 2048);
          const int kb = (kbyte0 + (kk << 6)) ^ swz;
          frag8 b0 = *(const frag8*)(w0r + kb);
          frag8 b1 = *(const frag8*)(w1r + kb);
          acc0 = __builtin_amdgcn_mfma_f32_16x16x32_bf16(af, b0, acc0, 0, 0, 0);
          acc1 = __builtin_amdgcn_mfma_f32_16x16x32_bf16(af, b1, acc1, 0, 0, 0);
        }
      }
    } else {
      #pragma unroll 8
      for (int kk = 0; kk < 32; ++kk) {
        frag8 af = *(const frag8*)(apb + kk * 2048);
        const int kb = (kbyte0 + (kk << 6)) ^ swz;
        frag8 b0 = *(const frag8*)(w0r + kb);
        frag8 b1 = *(const frag8*)(w1r + kb);
        acc0 = __builtin_amdgcn_mfma_f32_16x16x32_bf16(af, b0, acc0, 0, 0, 0);
        acc1 = __builtin_amdgcn_mfma_f32_16x16x32_bf16(af, b1, acc1, 0, 0, 0);
      }
    }
  }
  float* g = gl + kh * (64 * 32);
  const int orow = mt * 16 + lgr * 4;
  #pragma unroll
  for (int r = 0; r < 4; ++r) {
    g[(orow + r) * 32 + l15]      = acc0[r];
    g[(orow + r) * 32 + 16 + l15] = acc1[r];
  }
  __syncthreads();

  const int row = tid >> 3, ul = tid & 7;
  f4 p0 = *(const f4*)(gl + row * 32 + ul * 4);
  f4 p1 = *(const f4*)(gl + 64 * 32 + row * 32 + ul * 4);
  float iv = p0.x + p1.x + bias.x;
  float fv = p0.y + p1.y + bias.y;
  float gv = p0.z + p1.z + bias.z;
  float ov = p0.w + p1.w + bias.w;
  float cn = sigm(fv) * c_reg + sigm(iv) * tanhf(gv);
  float hh = sigm(ov) * tanhf(cn);
  c_reg = cn;
  // pack the 8-unit row (16B) with shfl_xor; one dwordx4 per row (ul==0)
  // PERMUTED dst: hout + ug0*64 + row*8  (WG block is 1KB contiguous)
  unsigned hv = (unsigned)f2b(hh);
  unsigned a  = hv | (__shfl_xor(hv, 1) << 16);   // (u, u+1) at even ul
  unsigned b  = __shfl_xor(a, 2);                 // (u2,u3) at ul0
  unsigned c2 = __shfl_xor(a, 4);                 // (u4,u5) at ul0
  unsigned d2 = __shfl_xor(b, 4);                 // (u6,u7) at ul0
  if (ul == 0) {
    i4 w; w.x = (int)a; w.y = (int)b; w.z = (int)c2; w.w = (int)d2;
    stcoh4(hout + ug0 * 64 + row * 8, w);
  }
  if (fout) fout[(long)row * fstride + ug0 + ul] = hh;
  // NOTE: gl WAR protection comes from wg_arrive()'s __syncthreads.
}

// ---------------- VAE head, one (s,l,b) per WG ------------------------------
// h inputs/outputs are in PERMUTED layout; c in natural layout.
__device__ __forceinline__ void vae_wg(
    int bid, char* scr,
    const u16* h0f, const u16* h1f, const float* c0f, const float* c1f,
    const float* hmuW, const float* hmub, const float* hsgW, const float* hsgb,
    const float* houtW, const float* houtb,
    const float* cmuW, const float* cmub, const float* csgW, const float* csgb,
    const float* coutW, const float* coutb,
    const float* eps_h, const float* eps_c,
    float* muo, float* sgo, u16* hd0, u16* hd1, float* cd0, float* cd1)
{
  float* hrow = (float*)scr;
  float* muv  = hrow + 1024;
  float* sgv  = muv + 128;
  float* zz   = sgv + 128;
  const int tid = threadIdx.x;
  const int b = bid & 63, l = (bid >> 6) & 1, s = bid >> 7;

  if (s == 0) {
    const u16* h = l ? h1f : h0f;
    for (int i = tid; i < D_; i += 512)
      hrow[i] = b2f(h[(i >> 3) * 512 + b * 8 + (i & 7)]);
  } else {
    const float* c = (l ? c1f : c0f) + b * D_;
    for (int i = tid; i < D_; i += 512) hrow[i] = c[i];
  }
  __syncthreads();

  const float* muW = (s ? cmuW : hmuW) + (long)l * G_ * D_;
  const float* sgW = (s ? csgW : hsgW) + (long)l * G_ * D_;
  const float* mub = (s ? cmub : hmub) + l * G_;
  const float* sgb = (s ? csgb : hsgb) + l * G_;
  const int wv = tid >> 6, lane = tid & 63;
  for (int oi = wv; oi < 2 * G_; oi += 8) {
    const int g = (oi < G_) ? oi : oi - G_;
    const float* Wr = ((oi < G_) ? muW : sgW) + (long)g * D_;
    float d = 0.f;
    for (int j = lane; j < D_; j += 64) d += Wr[j] * hrow[j];
    for (int off = 1; off < 64; off <<= 1) d += __shfl_xor(d, off);
    if (lane == 0) {
      if (oi < G_) muv[g] = d + mub[g]; else sgv[g] = d + sgb[g];
    }
  }
  __syncthreads();
  if (tid < G_) {
    const int g = tid;
    const float mu = muv[g], sg = sgv[g];
    const float* ep = (s ? eps_c : eps_h) + ((long)l * B_ + b) * G_;
    zz[g] = mu + ep[g] * __expf(sg);
    muo[(long)bid * G_ + g] = mu;
    sgo[(long)bid * G_ + g] = sg;
  }
  __syncthreads();
  const float* oW  = (s ? coutW : houtW) + (long)l * D_ * G_;
  const float* obv = (s ? coutb : houtb) + l * D_;
  for (int i = 0; i < 2; ++i) {
    const int dd = i * 512 + tid;
    float acc = obv[dd];
    const float* Wr = oW + (long)dd * G_;
    #pragma unroll 4
    for (int g = 0; g < G_; ++g) acc += zz[g] * Wr[g];
    if (s == 0) {
      (l ? hd1 : hd0)[(dd >> 3) * 512 + b * 8 + (dd & 7)] = f2b(acc);
    } else {
      (l ? cd1 : cd0)[b * D_ + dd] = acc;
    }
  }
  __syncthreads();
}

// ---------------- the persistent kernel -------------------------------------
__global__ __launch_bounds__(512, 1)
void persist(const u16* __restrict__ Wpe, const u16* __restrict__ Wpd,
             const float* __restrict__ bp,
             const u16* __restrict__ xb, const u16* __restrict__ xd0,
             u16* ring0, u16* ring1,
             float* ce0, float* ce1,
             u16* hd0i, u16* hd1i, float* cd0, float* cd1,
             const float* hmuW, const float* hmub, const float* hsgW, const float* hsgb,
             const float* houtW, const float* houtb,
             const float* cmuW, const float* cmub, const float* csgW, const float* csgb,
             const float* coutW, const float* coutb,
             const float* eps_h, const float* eps_c,
             float* out, float* muo, float* sgo, unsigned* bar)
{
  __shared__ __align__(16) char smem[147456 + 64]; // 128K weights + 16K + flags
  char*  wlds = smem;
  float* gl   = (float*)(smem + 131072);
  unsigned* lsf = (unsigned*)(smem + 147456);      // [0]=sig0 flag, [1]=sig1

  unsigned* gcnt = bar;
  unsigned* acnt = bar + 2048;
  unsigned* bcnt = bar + 4096;
  unsigned* ccnt = bar + 6144;
  unsigned* dcnt = bar + 8192;

  const int wg  = blockIdx.x;
  const bool isL0 = (wg < 128);
  const int wgL = wg & 127;
  const int ug0 = wgL * 8;
  const int tid = threadIdx.x;
  const int aline = wgL >> 3;       // arrival line = column chunk of this WG

  // ---- encoder phase (signal-driven, no grid barriers) ----
  if (tid == 0) { lsf[0] = 0; lsf[1] = 0; }        // load_weights syncs
  load_weights(Wpe + (isL0 ? 0l : (long)FD * K2) + (long)wgL * 32 * K2, wlds);
  f4 bias = *(const f4*)(bp + (isL0 ? 0 : FD) + (ug0 + (tid & 7)) * 4);
  float c_reg = 0.f;

  if (isL0) {
    for (int s = 0; s < T_; ++s) {
      cellw(xb + (long)s * BD, nullptr, 0,
            s ? (ring0 + (long)(s - 1) * BD) : nullptr,
            s ? acnt : nullptr, 8u * (unsigned)s,
            wlds, gl, lsf, (unsigned)(s + 1),
            c_reg, bias, ug0,
            ring0 + (long)s * BD, nullptr, 0);
      wg_arrive(acnt, aline);
    }
  } else {
    for (int t = 0; t < T_; ++t) {
      cellw(ring0 + (long)t * BD, acnt, 8u * (unsigned)(t + 1),
            t ? (ring1 + (long)(t - 1) * BD) : nullptr,
            t ? bcnt : nullptr, 8u * (unsigned)t,
            wlds, gl, lsf, (unsigned)(t + 1),
            c_reg, bias, ug0,
            ring1 + (long)t * BD, nullptr, 0);
      wg_arrive(bcnt, aline);
    }
  }
  // publish final c (normal stores; fenced sync follows)
  {
    const int row = tid >> 3, ul = tid & 7;
    (isL0 ? ce0 : ce1)[row * D_ + ug0 + ul] = c_reg;
  }
  fullsync(gcnt, 1, wg, true);

  // ---- VAE ----
  vae_wg(wg, (char*)gl,
         ring0 + 255l * BD, ring1 + 255l * BD, ce0, ce1,
         hmuW, hmub, hsgW, hsgb, houtW, houtb,
         cmuW, cmub, csgW, csgb, coutW, coutb,
         eps_h, eps_c, muo, sgo, hd0i, hd1i, cd0, cd1);
  fullsync(gcnt, 2, wg, true);   // also invalidates encoder-era ring lines

  // ---- decoder phase (signal-driven, 2 handoffs/step) ----
  if (tid == 0) { lsf[0] = 0; lsf[1] = 0; }        // load_weights syncs
  load_weights(Wpd + (isL0 ? 0l : (long)FD * K2) + (long)wgL * 32 * K2, wlds);
  bias = *(const f4*)(bp + 2 * FD + (isL0 ? 0 : FD) + (ug0 + (tid & 7)) * 4);
  {
    const int row = tid >> 3, ul = tid & 7;
    c_reg = (isL0 ? cd0 : cd1)[row * D_ + ug0 + ul];
  }

  if (isL0) {
    for (int t = 0; t < T_; ++t) {
      cellw(t ? (ring1 + (long)(t - 1) * BD) : xd0,
            t ? dcnt : nullptr, 8u * (unsigned)t,
            t ? (ring0 + (long)(t - 1) * BD) : hd0i,
            t ? ccnt : nullptr, 8u * (unsigned)t,
            wlds, gl, lsf, (unsigned)(t + 1),
            c_reg, bias, ug0,
            ring0 + (long)t * BD, nullptr, 0);
      wg_arrive(ccnt, aline);
    }
  } else {
    for (int t = 0; t < T_; ++t) {
      cellw(ring0 + (long)t * BD, ccnt, 8u * (unsigned)(t + 1),
            t ? (ring1 + (long)(t - 1) * BD) : hd1i,
            t ? dcnt : nullptr, 8u * (unsigned)t,
            wlds, gl, lsf, (unsigned)(t + 1),
            c_reg, bias, ug0,
            ring1 + (long)t * BD, out + (long)t * D_, (long)T_ * D_);
      wg_arrive(dcnt, aline);
    }
  }
}

// ---------------------------------------------------------------------------
// Spectral norm prepass (unchanged, verified)
// ---------------------------------------------------------------------------
__device__ __forceinline__ const float* selW(int m, const float* a, const float* b,
                                             const float* c, const float* d) {
  const float* W;
  switch (m >> 1) { case 0: W = a; break; case 1: W = b; break;
                    case 2: W = c; break; default: W = d; }
  return W + (long)(m & 1) * FD * D_;
}
__device__ __forceinline__ const float* selU(int m, const float* a, const float* b,
                                             const float* c, const float* d) {
  const float* u;
  switch (m >> 1) { case 0: u = a; break; case 1: u = b; break;
                    case 2: u = c; break; default: u = d; }
  return u + (m & 1) * FD;
}

__global__ __launch_bounds__(256)
void k_unorm(const float* euih, const float* euhh, const float* duih, const float* duhh,
             float* uinv)
{
  const int m = blockIdx.x;
  const float* u = selU(m, euih, euhh, duih, duhh);
  float s = 0.f;
  for (int i = threadIdx.x; i < FD; i += 256) { float v = u[i]; s += v * v; }
  __shared__ float red[4];
  for (int off = 1; off < 64; off <<= 1) s += __shfl_xor(s, off);
  if ((threadIdx.x & 63) == 0) red[threadIdx.x >> 6] = s;
  __syncthreads();
  if (threadIdx.x == 0)
    uinv[m] = 1.0f / (sqrtf(red[0] + red[1] + red[2] + red[3]) + 1e-12f);
}

__global__ __launch_bounds__(256)
void k_v(const float* eWih, const float* eWhh, const float* dWih, const float* dWhh,
         const float* euih, const float* euhh, const float* duih, const float* duhh,
         const float* uinv, float* v, float* vss)
{
  __shared__ float us[FD];
  __shared__ float red[4];
  const int m = blockIdx.x >> 2, cb = blockIdx.x & 3;
  const float* W = selW(m, eWih, eWhh, dWih, dWhh);
  const float* u = selU(m, euih, euhh, duih, duhh);
  for (int i = threadIdx.x; i < FD; i += 256) us[i] = u[i];
  __syncthreads();
  const int j = cb * 256 + threadIdx.x;
  float acc = 0.f;
  for (int i = 0; i < FD; ++i) acc += W[(long)i * D_ + j] * us[i];
  acc *= uinv[m];
  v[m * D_ + j] = acc;
  float s = acc * acc;
  for (int off = 1; off < 64; off <<= 1) s += __shfl_xor(s, off);
  if ((threadIdx.x & 63) == 0) red[threadIdx.x >> 6] = s;
  __syncthreads();
  if (threadIdx.x == 0) vss[blockIdx.x] = red[0] + red[1] + red[2] + red[3];
}

__global__ __launch_bounds__(256)
void k_sig(const float* eWih, const float* eWhh, const float* dWih, const float* dWhh,
           const float* v, float* sgp)
{
  __shared__ float vl[D_];
  __shared__ float red[4];
  const int m = blockIdx.x >> 6, rb = blockIdx.x & 63;
  const float* W = selW(m, eWih, eWhh, dWih, dWhh);
  for (int i = threadIdx.x; i < D_; i += 256) vl[i] = v[m * D_ + i];
  __syncthreads();
  const int wv = threadIdx.x >> 6, lane = threadIdx.x & 63;
  float ssq = 0.f;
  for (int rr = 0; rr < 16; ++rr) {
    const int r = rb * 64 + wv * 16 + rr;
    const float* Wr = W + (long)r * D_;
    float d = 0.f;
    for (int j = lane; j < D_; j += 64) d += Wr[j] * vl[j];
    for (int off = 1; off < 64; off <<= 1) d += __shfl_xor(d, off);
    ssq += d * d;
  }
  if (lane == 0) red[wv] = ssq;
  __syncthreads();
  if (threadIdx.x == 0) sgp[blockIdx.x] = red[0] + red[1] + red[2] + red[3];
}

__global__ void k_fin(const float* vss, const float* sgp, float* rsig)
{
  const int m = threadIdx.x;
  if (m < 8) {
    float vn = sqrtf(vss[m * 4] + vss[m * 4 + 1] + vss[m * 4 + 2] + vss[m * 4 + 3]);
    float s2 = 0.f;
    for (int i = 0; i < 64; ++i) s2 += sgp[m * 64 + i];
    rsig[m] = (vn + 1e-12f) / sqrtf(s2);   // 1/sigma
  }
}

__global__ __launch_bounds__(256)
void k_pack(const float* eWih, const float* eWhh, const float* dWih, const float* dWhh,
            const float* rsig, u16* Wpe, u16* Wpd)
{
  const long idx = (long)blockIdx.x * 256 + threadIdx.x;
  const int k8   = (int)(idx & 255);
  const int np   = (int)((idx >> 8) & 4095);
  const int pair = (int)(idx >> 20);
  const int l = pair & 1, ed = pair >> 1;
  const int u = np >> 2, g = np & 3;
  const int srow = g * D_ + u;
  const int k = k8 * 8;
  const float* src; float sc;
  if (k < D_) {
    const float* Wih = ed ? dWih : eWih;
    src = Wih + ((long)(l * FD + srow)) * D_ + k;
    sc  = rsig[ed ? 4 + l : l];
  } else {
    const float* Whh = ed ? dWhh : eWhh;
    src = Whh + ((long)(l * FD + srow)) * D_ + (k - D_);
    sc  = rsig[ed ? 6 + l : 2 + l];
  }
  f4 a = *(const f4*)src;
  f4 b = *(const f4*)(src + 4);
  frag8 o;
  o[0] = (short)f2b(a.x * sc); o[1] = (short)f2b(a.y * sc);
  o[2] = (short)f2b(a.z * sc); o[3] = (short)f2b(a.w * sc);
  o[4] = (short)f2b(b.x * sc); o[5] = (short)f2b(b.y * sc);
  o[6] = (short)f2b(b.z * sc); o[7] = (short)f2b(b.w * sc);
  u16* dst = (ed ? Wpd : Wpe) + ((long)(l * FD + np)) * K2 + k;
  *(frag8*)dst = o;
}

__global__ void k_packb(const float* eb, const float* db, float* bp)
{
  const int idx = blockIdx.x * 256 + threadIdx.x;   // 4*4096
  const int j = idx & 4095, pair = idx >> 12;
  const int l = pair & 1, ed = pair >> 1;
  const float* b = (ed ? db : eb) + l * FD;
  bp[pair * FD + j] = b[(j & 3) * D_ + (j >> 2)];
}

// x [B,T,D] f32 -> xb PERMUTED: xb[t][(m*64+b)*8+u] = x[b][t][m*8+u]
__global__ __launch_bounds__(512)
void k_xb(const float* __restrict__ x, u16* __restrict__ xb)
{
  const long i8 = ((long)blockIdx.x * 512 + threadIdx.x) * 8;
  const int t   = (int)(i8 >> 16);           // / BD
  const int rem = (int)(i8 & 65535);
  const int m   = rem >> 9;
  const int b   = (rem >> 3) & 63;
  const float* src = x + ((long)b * T_ + t) * D_ + m * 8;
  f4 a = *(const f4*)src;
  f4 c = *(const f4*)(src + 4);
  frag8 o;
  o[0] = (short)f2b(a.x); o[1] = (short)f2b(a.y);
  o[2] = (short)f2b(a.z); o[3] = (short)f2b(a.w);
  o[4] = (short)f2b(c.x); o[5] = (short)f2b(c.y);
  o[6] = (short)f2b(c.z); o[7] = (short)f2b(c.w);
  *(frag8*)(xb + i8) = o;
}

// initial [1,D] -> xd0 PERMUTED broadcast over b
__global__ __launch_bounds__(512)
void k_xd0(const float* __restrict__ initial, u16* __restrict__ xd0)
{
  const int i8 = (blockIdx.x * 512 + threadIdx.x) * 8;   // < 65536
  const int m  = i8 >> 9;
  f4 a = *(const f4*)(initial + m * 8);
  f4 c = *(const f4*)(initial + m * 8 + 4);
  frag8 o;
  o[0] = (short)f2b(a.x); o[1] = (short)f2b(a.y);
  o[2] = (short)f2b(a.z); o[3] = (short)f2b(a.w);
  o[4] = (short)f2b(c.x); o[5] = (short)f2b(c.y);
  o[6] = (short)f2b(c.z); o[7] = (short)f2b(c.w);
  *(frag8*)(xd0 + i8) = o;
}

// ---------------------------------------------------------------------------
extern "C" void kernel_launch(void* const* d_in, const int* in_sizes, int n_in,
                              void* d_out, int out_size, void* d_ws, size_t ws_size,
                              hipStream_t stream)
{
  const float* x       = (const float*)d_in[0];
  const float* initial = (const float*)d_in[1];
  const float* eWih    = (const float*)d_in[2];
  const float* eWhh    = (const float*)d_in[3];
  const float* eb      = (const float*)d_in[4];
  const float* euih    = (const float*)d_in[5];
  const float* euhh    = (const float*)d_in[6];
  const float* dWih    = (const float*)d_in[7];
  const float* dWhh    = (const float*)d_in[8];
  const float* db      = (const float*)d_in[9];
  const float* duih    = (const float*)d_in[10];
  const float* duhh    = (const float*)d_in[11];
  const float* hmuW    = (const float*)d_in[12];
  const float* hmub    = (const float*)d_in[13];
  const float* hsgW    = (const float*)d_in[14];
  const float* hsgb    = (const float*)d_in[15];
  const float* houtW   = (const float*)d_in[16];
  const float* houtb   = (const float*)d_in[17];
  const float* cmuW    = (const float*)d_in[18];
  const float* cmub    = (const float*)d_in[19];
  const float* csgW    = (const float*)d_in[20];
  const float* csgb    = (const float*)d_in[21];
  const float* coutW   = (const float*)d_in[22];
  const float* coutb   = (const float*)d_in[23];
  const float* eps_h   = (const float*)d_in[24];
  const float* eps_c   = (const float*)d_in[25];

  char* w = (char*)d_ws;
  auto alloc = [&](size_t n) -> char* {
    char* p = w; w += (n + 255) & ~(size_t)255; return p;
  };
  u16*   Wpe   = (u16*)  alloc(2l * FD * K2 * 2);       // 32 MB
  u16*   Wpd   = (u16*)  alloc(2l * FD * K2 * 2);       // 32 MB
  u16*   xb    = (u16*)  alloc((long)T_ * BD * 2);      // 32 MB
  u16*   ring0 = (u16*)  alloc((long)T_ * BD * 2);      // 32 MB
  u16*   ring1 = (u16*)  alloc((long)T_ * BD * 2);      // 32 MB
  u16*   xd0   = (u16*)  alloc((long)BD * 2);
  u16*   hd0i  = (u16*)  alloc((long)BD * 2);
  u16*   hd1i  = (u16*)  alloc((long)BD * 2);
  float* ce0   = (float*)alloc((long)BD * 4);
  float* ce1   = (float*)alloc((long)BD * 4);
  float* cd0   = (float*)alloc((long)BD * 4);
  float* cd1   = (float*)alloc((long)BD * 4);
  float* bp    = (float*)alloc(4l * FD * 4);
  float* vv    = (float*)alloc(8l * D_ * 4);
  float* uinv  = (float*)alloc(64);
  float* vss   = (float*)alloc(256);
  float* sgp   = (float*)alloc(4096);
  float* rsig  = (float*)alloc(64);
  unsigned* bar = (unsigned*)alloc(40960);   // 5 sets x 16 lines x 512B

  hipMemsetAsync(bar, 0, 40960, stream);

  k_unorm<<<8,    256, 0, stream>>>(euih, euhh, duih, duhh, uinv);
  k_v    <<<32,   256, 0, stream>>>(eWih, eWhh, dWih, dWhh, euih, euhh, duih, duhh,
                                    uinv, vv, vss);
  k_sig  <<<512,  256, 0, stream>>>(eWih, eWhh, dWih, dWhh, vv, sgp);
  k_fin  <<<1,    64,  0, stream>>>(vss, sgp, rsig);
  k_pack <<<16384,256, 0, stream>>>(eWih, eWhh, dWih, dWhh, rsig, Wpe, Wpd);
  k_packb<<<64,   256, 0, stream>>>(eb, db, bp);
  k_xb   <<<4096, 512, 0, stream>>>(x, xb);
  k_xd0  <<<16,   512, 0, stream>>>(initial, xd0);

  float* out = (float*)d_out;
  float* muo = out + (long)B_ * T_ * D_;
  float* sgo = muo + 4l * B_ * G_;

  persist<<<NWG, 512, 0, stream>>>(Wpe, Wpd, bp, xb, xd0,
                                   ring0, ring1,
                                   ce0, ce1, hd0i, hd1i, cd0, cd1,
                                   hmuW, hmub, hsgW, hsgb, houtW, houtb,
                                   cmuW, cmub, csgW, csgb, coutW, coutb,
                                   eps_h, eps_c, out, muo, sgo, bar);
}

// Round 14
// 5021.358 us; speedup vs baseline: 2.1800x; 1.1777x over previous
//
#include <hip/hip_runtime.h>

// LSTM-VAE  B=64 T=256 D=1024 L=2 G=128 — persistent kernel, signal-driven.
// Round 14: both-halves-split-8-ways (each wave: 16 kk free + 16 kk gated)
// + 8-chunk (2-line) gated waits -> post-detect serial tail drops 16->4 kk.
#define B_  64
#define T_  256
#define D_  1024
#define G_  128
#define FD  4096   // 4*D
#define K2  2048   // D (ih) + D (hh)
#define BD  65536  // B_*D_
#define NWG 256
#define CL  128    // u32 stride between counter lines (512 B)

typedef unsigned short u16;
typedef __attribute__((ext_vector_type(8))) short frag8;  // 8 bf16
typedef __attribute__((ext_vector_type(4))) float f4;
typedef __attribute__((ext_vector_type(4))) int i4;

__device__ __forceinline__ u16 f2b(float f) {
  unsigned u = __float_as_uint(f);
  u += 0x7fffu + ((u >> 16) & 1u);
  return (u16)(u >> 16);
}
__device__ __forceinline__ float b2f(u16 s) {
  return __uint_as_float(((unsigned)s) << 16);
}
__device__ __forceinline__ float sigm(float x) { return 1.0f / (1.0f + __expf(-x)); }

// write-through coherent 16B store (lands at LLC once vmcnt drains)
__device__ __forceinline__ void stcoh4(void* p, i4 w) {
  asm volatile("global_store_dwordx4 %0, %1, off sc0 sc1"
               :: "v"(p), "v"(w) : "memory");
}

// ---------------- group-signal primitives -----------------------------------
// lanes 0..1 poll 2 counter lines [base, base+2); publish val to LDS flag.
__device__ __forceinline__ void poll2_pub(const unsigned* s, int base,
                                          unsigned tgt, unsigned* lf,
                                          unsigned val) {
  const int l = threadIdx.x & 63;
  for (;;) {
    bool ok = true;
    if (l < 2)
      ok = __hip_atomic_load(&s[(base + l) * CL], __ATOMIC_RELAXED,
                             __HIP_MEMORY_SCOPE_AGENT) >= tgt;
    if (__all(ok)) break;
    __builtin_amdgcn_s_sleep(1);
  }
  if (l == 0)
    __hip_atomic_store(lf, val, __ATOMIC_RELAXED, __HIP_MEMORY_SCOPE_WORKGROUP);
  asm volatile("" ::: "memory");
}

// lanes 0..15 poll all 16 lines; publish val to LDS flag.
__device__ __forceinline__ void poll16_pub(const unsigned* s, unsigned tgt,
                                           unsigned* lf, unsigned val) {
  const int l = threadIdx.x & 63;
  for (;;) {
    bool ok = true;
    if (l < 16)
      ok = __hip_atomic_load(&s[l * CL], __ATOMIC_RELAXED,
                             __HIP_MEMORY_SCOPE_AGENT) >= tgt;
    if (__all(ok)) break;
    __builtin_amdgcn_s_sleep(1);
  }
  if (l == 0)
    __hip_atomic_store(lf, val, __ATOMIC_RELAXED, __HIP_MEMORY_SCOPE_WORKGROUP);
  asm volatile("" ::: "memory");
}

// Sibling waves: spin on the LDS flag (no fabric traffic).
__device__ __forceinline__ void lds_wait(const unsigned* lf, unsigned seq) {
  while (__hip_atomic_load(lf, __ATOMIC_RELAXED,
                           __HIP_MEMORY_SCOPE_WORKGROUP) < seq)
    __builtin_amdgcn_s_sleep(1);
  asm volatile("" ::: "memory");
}

// arrive: drain this WG's (coherent) stores, then one atomic add to `line`.
__device__ __forceinline__ void wg_arrive(unsigned* cnt, int line) {
  asm volatile("s_waitcnt vmcnt(0)" ::: "memory");
  __syncthreads();
  if (threadIdx.x == 0)
    __hip_atomic_fetch_add(&cnt[line * CL], 1u, __ATOMIC_RELAXED,
                           __HIP_MEMORY_SCOPE_AGENT);
}

// full-wave poll for phase-edge syncs (rare)
__device__ __forceinline__ void wave_wait16(const unsigned* cnt, unsigned tgt) {
  const int l = threadIdx.x & 63;
  if (l < 16) {
    while (__hip_atomic_load(&cnt[l * CL], __ATOMIC_RELAXED,
                             __HIP_MEMORY_SCOPE_AGENT) < tgt)
      __builtin_amdgcn_s_sleep(2);
  }
  asm volatile("" ::: "memory");
}

// full-grid sync (phase edges only); fenced = release/acquire cache ops
__device__ __forceinline__ void fullsync(unsigned* g, unsigned ep, int wg,
                                         bool fenced) {
  if (fenced) __builtin_amdgcn_fence(__ATOMIC_RELEASE, "agent");
  wg_arrive(g, wg & 15);
  wave_wait16(g, ep * 16u);
  __syncthreads();
  if (fenced) {
    __builtin_amdgcn_fence(__ATOMIC_ACQUIRE, "agent");
    __syncthreads();
  }
}

// ---------------- weight slice load: 32 rows x 2048 bf16, XOR-swizzled ------
__device__ __forceinline__ void load_weights(const u16* __restrict__ Wg, char* wlds) {
  const int t  = threadIdx.x;
  const int r  = t >> 4;           // 0..31
  const int c0 = t & 15;
  const char* src = (const char*)(Wg + (long)r * K2);
  char* dstrow = wlds + (r << 12);
  const int swz = (r & 7) << 4;
  #pragma unroll
  for (int i = 0; i < 16; ++i) {
    const int cb = (c0 + (i << 4)) << 4;      // chunk byte offset
    frag8 v = *(const frag8*)(src + cb);
    *(frag8*)(dstrow + (cb ^ swz)) = v;
  }
  __syncthreads();
}

// ---------------- one LSTM cell, 8-chunk / split-waves ----------------------
// A operands PERMUTED: A[(m*64+row)*8+u]. Wave (mt=wv&3, ks=wv>>2) covers rows
// mt*16..+16 and kk slice [ks*16, ks*16+16) of EACH operand.
// A1 = own-group operand, single gate (c1p,t1). A0 = cross-group operand,
// 8-chunk gate (c0p,t0): chunk cc (kk 4cc..4cc+4) gated by lines [2cc,2cc+2).
// a0half: weight K-half of A0 (0 = bytes [0,2048), 1 = [2048,4096)).
// Flags: lsf[0]=A0/ks0, lsf[1]=A0/ks1, lsf[2]=A1. Pollers are mt==0 waves.
__device__ __forceinline__ void cellw(
    const u16* __restrict__ A0, const unsigned* c0p, unsigned t0, int a0half,
    const u16* __restrict__ A1, const unsigned* c1p, unsigned t1,
    const char* wlds, float* gl, unsigned* lsf, unsigned seq,
    float& c_reg, const f4& bias, int ug0,
    u16* __restrict__ hout, float* __restrict__ fout, long fstride)
{
  const int tid = threadIdx.x;
  const int lane = tid & 63, wv = tid >> 6;
  const int mt = wv & 3, ks = wv >> 2;
  const int l15 = lane & 15, lgr = lane >> 4;

  f4 acc0 = (f4){0.f,0.f,0.f,0.f}, acc1 = (f4){0.f,0.f,0.f,0.f};
  const int lbase = (lgr * 64 + mt * 16 + l15) * 8;
  const int kwb = lgr << 4;
  const int swz = (l15 & 7) << 4;
  const char* w0r = wlds + ((long)l15 << 12);
  const char* w1r = wlds + ((long)(16 + l15) << 12);
  const int kk0 = ks * 16;

#define MM1(AP, HB, KK) {                                                      \
    frag8 af = *(const frag8*)((AP) + lbase + (KK) * 2048);                    \
    const int kb = ((HB) + ((KK) << 6) + kwb) ^ swz;                           \
    frag8 b0 = *(const frag8*)(w0r + kb);                                      \
    frag8 b1 = *(const frag8*)(w1r + kb);                                      \
    acc0 = __builtin_amdgcn_mfma_f32_16x16x32_bf16(af, b0, acc0, 0, 0, 0);     \
    acc1 = __builtin_amdgcn_mfma_f32_16x16x32_bf16(af, b1, acc1, 0, 0, 0); }

  // ---- A1 (own-group / free) first: 16 kk, single gate ----
  if (A1) {
    const int hb1 = (1 - a0half) << 11;
    if (c1p) {
      if (wv == 0) poll16_pub(c1p, t1, &lsf[2], seq);
      else         lds_wait(&lsf[2], seq);
    }
    #pragma unroll 8
    for (int kk = kk0; kk < kk0 + 16; ++kk) MM1(A1, hb1, kk)
  }
  // ---- A0 (cross-group / gated): 16 kk, 4 chunks of 4 kk ----
  if (A0) {
    const int hb0 = a0half << 11;
    if (c0p) {
      const unsigned fb = 4u * (seq - 1u);
      unsigned* lf = &lsf[ks];
      #pragma unroll
      for (int cl = 0; cl < 4; ++cl) {
        const int cc = ks * 4 + cl;
        const unsigned val = fb + (unsigned)cl + 1u;
        if (mt == 0) poll2_pub(c0p, cc * 2, t0, lf, val);
        else         lds_wait(lf, val);
        #pragma unroll
        for (int kk = cc * 4; kk < cc * 4 + 4; ++kk) MM1(A0, hb0, kk)
      }
    } else {
      #pragma unroll 8
      for (int kk = kk0; kk < kk0 + 16; ++kk) MM1(A0, hb0, kk)
    }
  }
#undef MM1

  float* g = gl + ks * (64 * 32);
  const int orow = mt * 16 + lgr * 4;
  #pragma unroll
  for (int r = 0; r < 4; ++r) {
    g[(orow + r) * 32 + l15]      = acc0[r];
    g[(orow + r) * 32 + 16 + l15] = acc1[r];
  }
  __syncthreads();

  const int row = tid >> 3, ul = tid & 7;
  f4 p0 = *(const f4*)(gl + row * 32 + ul * 4);
  f4 p1 = *(const f4*)(gl + 64 * 32 + row * 32 + ul * 4);
  float iv = p0.x + p1.x + bias.x;
  float fv = p0.y + p1.y + bias.y;
  float gv = p0.z + p1.z + bias.z;
  float ov = p0.w + p1.w + bias.w;
  float cn = sigm(fv) * c_reg + sigm(iv) * tanhf(gv);
  float hh = sigm(ov) * tanhf(cn);
  c_reg = cn;
  // pack the 8-unit row (16B); one coherent dwordx4 per row (ul==0)
  unsigned hv = (unsigned)f2b(hh);
  unsigned a  = hv | (__shfl_xor(hv, 1) << 16);
  unsigned b  = __shfl_xor(a, 2);
  unsigned c2 = __shfl_xor(a, 4);
  unsigned d2 = __shfl_xor(b, 4);
  if (ul == 0) {
    i4 w; w.x = (int)a; w.y = (int)b; w.z = (int)c2; w.w = (int)d2;
    stcoh4(hout + ug0 * 64 + row * 8, w);
  }
  if (fout) fout[(long)row * fstride + ug0 + ul] = hh;
  // NOTE: gl WAR protection comes from wg_arrive()'s __syncthreads.
}

// ---------------- VAE head, one (s,l,b) per WG ------------------------------
// h inputs/outputs PERMUTED; c natural.
__device__ __forceinline__ void vae_wg(
    int bid, char* scr,
    const u16* h0f, const u16* h1f, const float* c0f, const float* c1f,
    const float* hmuW, const float* hmub, const float* hsgW, const float* hsgb,
    const float* houtW, const float* houtb,
    const float* cmuW, const float* cmub, const float* csgW, const float* csgb,
    const float* coutW, const float* coutb,
    const float* eps_h, const float* eps_c,
    float* muo, float* sgo, u16* hd0, u16* hd1, float* cd0, float* cd1)
{
  float* hrow = (float*)scr;
  float* muv  = hrow + 1024;
  float* sgv  = muv + 128;
  float* zz   = sgv + 128;
  const int tid = threadIdx.x;
  const int b = bid & 63, l = (bid >> 6) & 1, s = bid >> 7;

  if (s == 0) {
    const u16* h = l ? h1f : h0f;
    for (int i = tid; i < D_; i += 512)
      hrow[i] = b2f(h[(i >> 3) * 512 + b * 8 + (i & 7)]);
  } else {
    const float* c = (l ? c1f : c0f) + b * D_;
    for (int i = tid; i < D_; i += 512) hrow[i] = c[i];
  }
  __syncthreads();

  const float* muW = (s ? cmuW : hmuW) + (long)l * G_ * D_;
  const float* sgW = (s ? csgW : hsgW) + (long)l * G_ * D_;
  const float* mub = (s ? cmub : hmub) + l * G_;
  const float* sgb = (s ? csgb : hsgb) + l * G_;
  const int wv = tid >> 6, lane = tid & 63;
  for (int oi = wv; oi < 2 * G_; oi += 8) {
    const int g = (oi < G_) ? oi : oi - G_;
    const float* Wr = ((oi < G_) ? muW : sgW) + (long)g * D_;
    float d = 0.f;
    for (int j = lane; j < D_; j += 64) d += Wr[j] * hrow[j];
    for (int off = 1; off < 64; off <<= 1) d += __shfl_xor(d, off);
    if (lane == 0) {
      if (oi < G_) muv[g] = d + mub[g]; else sgv[g] = d + sgb[g];
    }
  }
  __syncthreads();
  if (tid < G_) {
    const int g = tid;
    const float mu = muv[g], sg = sgv[g];
    const float* ep = (s ? eps_c : eps_h) + ((long)l * B_ + b) * G_;
    zz[g] = mu + ep[g] * __expf(sg);
    muo[(long)bid * G_ + g] = mu;
    sgo[(long)bid * G_ + g] = sg;
  }
  __syncthreads();
  const float* oW  = (s ? coutW : houtW) + (long)l * D_ * G_;
  const float* obv = (s ? coutb : houtb) + l * D_;
  for (int i = 0; i < 2; ++i) {
    const int dd = i * 512 + tid;
    float acc = obv[dd];
    const float* Wr = oW + (long)dd * G_;
    #pragma unroll 4
    for (int g = 0; g < G_; ++g) acc += zz[g] * Wr[g];
    if (s == 0) {
      (l ? hd1 : hd0)[(dd >> 3) * 512 + b * 8 + (dd & 7)] = f2b(acc);
    } else {
      (l ? cd1 : cd0)[b * D_ + dd] = acc;
    }
  }
  __syncthreads();
}

// ---------------- the persistent kernel -------------------------------------
__global__ __launch_bounds__(512, 1)
void persist(const u16* __restrict__ Wpe, const u16* __restrict__ Wpd,
             const float* __restrict__ bp,
             const u16* __restrict__ xb, const u16* __restrict__ xd0,
             u16* ring0, u16* ring1,
             float* ce0, float* ce1,
             u16* hd0i, u16* hd1i, float* cd0, float* cd1,
             const float* hmuW, const float* hmub, const float* hsgW, const float* hsgb,
             const float* houtW, const float* houtb,
             const float* cmuW, const float* cmub, const float* csgW, const float* csgb,
             const float* coutW, const float* coutb,
             const float* eps_h, const float* eps_c,
             float* out, float* muo, float* sgo, unsigned* bar)
{
  __shared__ __align__(16) char smem[147456 + 64]; // 128K weights + 16K + flags
  char*  wlds = smem;
  float* gl   = (float*)(smem + 131072);
  unsigned* lsf = (unsigned*)(smem + 147456);      // [0]=A0ks0 [1]=A0ks1 [2]=A1

  unsigned* gcnt = bar;
  unsigned* acnt = bar + 2048;
  unsigned* bcnt = bar + 4096;
  unsigned* ccnt = bar + 6144;
  unsigned* dcnt = bar + 8192;

  const int wg  = blockIdx.x;
  const bool isL0 = (wg < 128);
  const int wgL = wg & 127;
  const int ug0 = wgL * 8;
  const int tid = threadIdx.x;
  const int aline = wgL >> 3;       // arrival line = column chunk of this WG

  // ---- encoder phase (signal-driven, no grid barriers) ----
  if (tid == 0) { lsf[0] = 0; lsf[1] = 0; lsf[2] = 0; }  // load_weights syncs
  load_weights(Wpe + (isL0 ? 0l : (long)FD * K2) + (long)wgL * 32 * K2, wlds);
  f4 bias = *(const f4*)(bp + (isL0 ? 0 : FD) + (ug0 + (tid & 7)) * 4);
  float c_reg = 0.f;

  if (isL0) {
    // A0 = ring0[s-1] (h-half, own-group, CHUNK-gated); A1 = xb[s] (free)
    for (int s = 0; s < T_; ++s) {
      cellw(s ? (ring0 + (long)(s - 1) * BD) : nullptr,
            s ? acnt : nullptr, 8u * (unsigned)s, 1,
            xb + (long)s * BD, nullptr, 0,
            wlds, gl, lsf, (unsigned)(s + 1),
            c_reg, bias, ug0,
            ring0 + (long)s * BD, nullptr, 0);
      wg_arrive(acnt, aline);
    }
  } else {
    // A0 = ring0[t] (x-half, cross-group, CHUNK-gated); A1 = ring1[t-1] (own)
    for (int t = 0; t < T_; ++t) {
      cellw(ring0 + (long)t * BD, acnt, 8u * (unsigned)(t + 1), 0,
            t ? (ring1 + (long)(t - 1) * BD) : nullptr,
            t ? bcnt : nullptr, 8u * (unsigned)t,
            wlds, gl, lsf, (unsigned)(t + 1),
            c_reg, bias, ug0,
            ring1 + (long)t * BD, nullptr, 0);
      wg_arrive(bcnt, aline);
    }
  }
  // publish final c (normal stores; fenced sync follows)
  {
    const int row = tid >> 3, ul = tid & 7;
    (isL0 ? ce0 : ce1)[row * D_ + ug0 + ul] = c_reg;
  }
  fullsync(gcnt, 1, wg, true);

  // ---- VAE ----
  vae_wg(wg, (char*)gl,
         ring0 + 255l * BD, ring1 + 255l * BD, ce0, ce1,
         hmuW, hmub, hsgW, hsgb, houtW, houtb,
         cmuW, cmub, csgW, csgb, coutW, coutb,
         eps_h, eps_c, muo, sgo, hd0i, hd1i, cd0, cd1);
  fullsync(gcnt, 2, wg, true);   // also invalidates encoder-era ring lines

  // ---- decoder phase (signal-driven, 2 handoffs/step) ----
  if (tid == 0) { lsf[0] = 0; lsf[1] = 0; lsf[2] = 0; }  // load_weights syncs
  load_weights(Wpd + (isL0 ? 0l : (long)FD * K2) + (long)wgL * 32 * K2, wlds);
  bias = *(const f4*)(bp + 2 * FD + (isL0 ? 0 : FD) + (ug0 + (tid & 7)) * 4);
  {
    const int row = tid >> 3, ul = tid & 7;
    c_reg = (isL0 ? cd0 : cd1)[row * D_ + ug0 + ul];
  }

  if (isL0) {
    // A0 = y[t-1] (x-half, cross-group, CHUNK-gated); A1 = ring0[t-1] (own)
    for (int t = 0; t < T_; ++t) {
      cellw(t ? (ring1 + (long)(t - 1) * BD) : xd0,
            t ? dcnt : nullptr, 8u * (unsigned)t, 0,
            t ? (ring0 + (long)(t - 1) * BD) : hd0i,
            t ? ccnt : nullptr, 8u * (unsigned)t,
            wlds, gl, lsf, (unsigned)(t + 1),
            c_reg, bias, ug0,
            ring0 + (long)t * BD, nullptr, 0);
      wg_arrive(ccnt, aline);
    }
  } else {
    // A0 = ring0[t] (x-half, cross-group, CHUNK-gated); A1 = ring1[t-1] (own)
    for (int t = 0; t < T_; ++t) {
      cellw(ring0 + (long)t * BD, ccnt, 8u * (unsigned)(t + 1), 0,
            t ? (ring1 + (long)(t - 1) * BD) : hd1i,
            t ? dcnt : nullptr, 8u * (unsigned)t,
            wlds, gl, lsf, (unsigned)(t + 1),
            c_reg, bias, ug0,
            ring1 + (long)t * BD, out + (long)t * D_, (long)T_ * D_);
      wg_arrive(dcnt, aline);
    }
  }
}

// ---------------------------------------------------------------------------
// Spectral norm prepass (unchanged, verified)
// ---------------------------------------------------------------------------
__device__ __forceinline__ const float* selW(int m, const float* a, const float* b,
                                             const float* c, const float* d) {
  const float* W;
  switch (m >> 1) { case 0: W = a; break; case 1: W = b; break;
                    case 2: W = c; break; default: W = d; }
  return W + (long)(m & 1) * FD * D_;
}
__device__ __forceinline__ const float* selU(int m, const float* a, const float* b,
                                             const float* c, const float* d) {
  const float* u;
  switch (m >> 1) { case 0: u = a; break; case 1: u = b; break;
                    case 2: u = c; break; default: u = d; }
  return u + (m & 1) * FD;
}

__global__ __launch_bounds__(256)
void k_unorm(const float* euih, const float* euhh, const float* duih, const float* duhh,
             float* uinv)
{
  const int m = blockIdx.x;
  const float* u = selU(m, euih, euhh, duih, duhh);
  float s = 0.f;
  for (int i = threadIdx.x; i < FD; i += 256) { float v = u[i]; s += v * v; }
  __shared__ float red[4];
  for (int off = 1; off < 64; off <<= 1) s += __shfl_xor(s, off);
  if ((threadIdx.x & 63) == 0) red[threadIdx.x >> 6] = s;
  __syncthreads();
  if (threadIdx.x == 0)
    uinv[m] = 1.0f / (sqrtf(red[0] + red[1] + red[2] + red[3]) + 1e-12f);
}

__global__ __launch_bounds__(256)
void k_v(const float* eWih, const float* eWhh, const float* dWih, const float* dWhh,
         const float* euih, const float* euhh, const float* duih, const float* duhh,
         const float* uinv, float* v, float* vss)
{
  __shared__ float us[FD];
  __shared__ float red[4];
  const int m = blockIdx.x >> 2, cb = blockIdx.x & 3;
  const float* W = selW(m, eWih, eWhh, dWih, dWhh);
  const float* u = selU(m, euih, euhh, duih, duhh);
  for (int i = threadIdx.x; i < FD; i += 256) us[i] = u[i];
  __syncthreads();
  const int j = cb * 256 + threadIdx.x;
  float acc = 0.f;
  for (int i = 0; i < FD; ++i) acc += W[(long)i * D_ + j] * us[i];
  acc *= uinv[m];
  v[m * D_ + j] = acc;
  float s = acc * acc;
  for (int off = 1; off < 64; off <<= 1) s += __shfl_xor(s, off);
  if ((threadIdx.x & 63) == 0) red[threadIdx.x >> 6] = s;
  __syncthreads();
  if (threadIdx.x == 0) vss[blockIdx.x] = red[0] + red[1] + red[2] + red[3];
}

__global__ __launch_bounds__(256)
void k_sig(const float* eWih, const float* eWhh, const float* dWih, const float* dWhh,
           const float* v, float* sgp)
{
  __shared__ float vl[D_];
  __shared__ float red[4];
  const int m = blockIdx.x >> 6, rb = blockIdx.x & 63;
  const float* W = selW(m, eWih, eWhh, dWih, dWhh);
  for (int i = threadIdx.x; i < D_; i += 256) vl[i] = v[m * D_ + i];
  __syncthreads();
  const int wv = threadIdx.x >> 6, lane = threadIdx.x & 63;
  float ssq = 0.f;
  for (int rr = 0; rr < 16; ++rr) {
    const int r = rb * 64 + wv * 16 + rr;
    const float* Wr = W + (long)r * D_;
    float d = 0.f;
    for (int j = lane; j < D_; j += 64) d += Wr[j] * vl[j];
    for (int off = 1; off < 64; off <<= 1) d += __shfl_xor(d, off);
    ssq += d * d;
  }
  if (lane == 0) red[wv] = ssq;
  __syncthreads();
  if (threadIdx.x == 0) sgp[blockIdx.x] = red[0] + red[1] + red[2] + red[3];
}

__global__ void k_fin(const float* vss, const float* sgp, float* rsig)
{
  const int m = threadIdx.x;
  if (m < 8) {
    float vn = sqrtf(vss[m * 4] + vss[m * 4 + 1] + vss[m * 4 + 2] + vss[m * 4 + 3]);
    float s2 = 0.f;
    for (int i = 0; i < 64; ++i) s2 += sgp[m * 64 + i];
    rsig[m] = (vn + 1e-12f) / sqrtf(s2);   // 1/sigma
  }
}

__global__ __launch_bounds__(256)
void k_pack(const float* eWih, const float* eWhh, const float* dWih, const float* dWhh,
            const float* rsig, u16* Wpe, u16* Wpd)
{
  const long idx = (long)blockIdx.x * 256 + threadIdx.x;
  const int k8   = (int)(idx & 255);
  const int np   = (int)((idx >> 8) & 4095);
  const int pair = (int)(idx >> 20);
  const int l = pair & 1, ed = pair >> 1;
  const int u = np >> 2, g = np & 3;
  const int srow = g * D_ + u;
  const int k = k8 * 8;
  const float* src; float sc;
  if (k < D_) {
    const float* Wih = ed ? dWih : eWih;
    src = Wih + ((long)(l * FD + srow)) * D_ + k;
    sc  = rsig[ed ? 4 + l : l];
  } else {
    const float* Whh = ed ? dWhh : eWhh;
    src = Whh + ((long)(l * FD + srow)) * D_ + (k - D_);
    sc  = rsig[ed ? 6 + l : 2 + l];
  }
  f4 a = *(const f4*)src;
  f4 b = *(const f4*)(src + 4);
  frag8 o;
  o[0] = (short)f2b(a.x * sc); o[1] = (short)f2b(a.y * sc);
  o[2] = (short)f2b(a.z * sc); o[3] = (short)f2b(a.w * sc);
  o[4] = (short)f2b(b.x * sc); o[5] = (short)f2b(b.y * sc);
  o[6] = (short)f2b(b.z * sc); o[7] = (short)f2b(b.w * sc);
  u16* dst = (ed ? Wpd : Wpe) + ((long)(l * FD + np)) * K2 + k;
  *(frag8*)dst = o;
}

__global__ void k_packb(const float* eb, const float* db, float* bp)
{
  const int idx = blockIdx.x * 256 + threadIdx.x;   // 4*4096
  const int j = idx & 4095, pair = idx >> 12;
  const int l = pair & 1, ed = pair >> 1;
  const float* b = (ed ? db : eb) + l * FD;
  bp[pair * FD + j] = b[(j & 3) * D_ + (j >> 2)];
}

// x [B,T,D] f32 -> xb PERMUTED: xb[t][(m*64+b)*8+u] = x[b][t][m*8+u]
__global__ __launch_bounds__(512)
void k_xb(const float* __restrict__ x, u16* __restrict__ xb)
{
  const long i8 = ((long)blockIdx.x * 512 + threadIdx.x) * 8;
  const int t   = (int)(i8 >> 16);           // / BD
  const int rem = (int)(i8 & 65535);
  const int m   = rem >> 9;
  const int b   = (rem >> 3) & 63;
  const float* src = x + ((long)b * T_ + t) * D_ + m * 8;
  f4 a = *(const f4*)src;
  f4 c = *(const f4*)(src + 4);
  frag8 o;
  o[0] = (short)f2b(a.x); o[1] = (short)f2b(a.y);
  o[2] = (short)f2b(a.z); o[3] = (short)f2b(a.w);
  o[4] = (short)f2b(c.x); o[5] = (short)f2b(c.y);
  o[6] = (short)f2b(c.z); o[7] = (short)f2b(c.w);
  *(frag8*)(xb + i8) = o;
}

// initial [1,D] -> xd0 PERMUTED broadcast over b
__global__ __launch_bounds__(512)
void k_xd0(const float* __restrict__ initial, u16* __restrict__ xd0)
{
  const int i8 = (blockIdx.x * 512 + threadIdx.x) * 8;   // < 65536
  const int m  = i8 >> 9;
  f4 a = *(const f4*)(initial + m * 8);
  f4 c = *(const f4*)(initial + m * 8 + 4);
  frag8 o;
  o[0] = (short)f2b(a.x); o[1] = (short)f2b(a.y);
  o[2] = (short)f2b(a.z); o[3] = (short)f2b(a.w);
  o[4] = (short)f2b(c.x); o[5] = (short)f2b(c.y);
  o[6] = (short)f2b(c.z); o[7] = (short)f2b(c.w);
  *(frag8*)(xd0 + i8) = o;
}

// ---------------------------------------------------------------------------
extern "C" void kernel_launch(void* const* d_in, const int* in_sizes, int n_in,
                              void* d_out, int out_size, void* d_ws, size_t ws_size,
                              hipStream_t stream)
{
  const float* x       = (const float*)d_in[0];
  const float* initial = (const float*)d_in[1];
  const float* eWih    = (const float*)d_in[2];
  const float* eWhh    = (const float*)d_in[3];
  const float* eb      = (const float*)d_in[4];
  const float* euih    = (const float*)d_in[5];
  const float* euhh    = (const float*)d_in[6];
  const float* dWih    = (const float*)d_in[7];
  const float* dWhh    = (const float*)d_in[8];
  const float* db      = (const float*)d_in[9];
  const float* duih    = (const float*)d_in[10];
  const float* duhh    = (const float*)d_in[11];
  const float* hmuW    = (const float*)d_in[12];
  const float* hmub    = (const float*)d_in[13];
  const float* hsgW    = (const float*)d_in[14];
  const float* hsgb    = (const float*)d_in[15];
  const float* houtW   = (const float*)d_in[16];
  const float* houtb   = (const float*)d_in[17];
  const float* cmuW    = (const float*)d_in[18];
  const float* cmub    = (const float*)d_in[19];
  const float* csgW    = (const float*)d_in[20];
  const float* csgb    = (const float*)d_in[21];
  const float* coutW   = (const float*)d_in[22];
  const float* coutb   = (const float*)d_in[23];
  const float* eps_h   = (const float*)d_in[24];
  const float* eps_c   = (const float*)d_in[25];

  char* w = (char*)d_ws;
  auto alloc = [&](size_t n) -> char* {
    char* p = w; w += (n + 255) & ~(size_t)255; return p;
  };
  u16*   Wpe   = (u16*)  alloc(2l * FD * K2 * 2);       // 32 MB
  u16*   Wpd   = (u16*)  alloc(2l * FD * K2 * 2);       // 32 MB
  u16*   xb    = (u16*)  alloc((long)T_ * BD * 2);      // 32 MB
  u16*   ring0 = (u16*)  alloc((long)T_ * BD * 2);      // 32 MB
  u16*   ring1 = (u16*)  alloc((long)T_ * BD * 2);      // 32 MB
  u16*   xd0   = (u16*)  alloc((long)BD * 2);
  u16*   hd0i  = (u16*)  alloc((long)BD * 2);
  u16*   hd1i  = (u16*)  alloc((long)BD * 2);
  float* ce0   = (float*)alloc((long)BD * 4);
  float* ce1   = (float*)alloc((long)BD * 4);
  float* cd0   = (float*)alloc((long)BD * 4);
  float* cd1   = (float*)alloc((long)BD * 4);
  float* bp    = (float*)alloc(4l * FD * 4);
  float* vv    = (float*)alloc(8l * D_ * 4);
  float* uinv  = (float*)alloc(64);
  float* vss   = (float*)alloc(256);
  float* sgp   = (float*)alloc(4096);
  float* rsig  = (float*)alloc(64);
  unsigned* bar = (unsigned*)alloc(40960);   // 5 sets x 16 lines x 512B

  hipMemsetAsync(bar, 0, 40960, stream);

  k_unorm<<<8,    256, 0, stream>>>(euih, euhh, duih, duhh, uinv);
  k_v    <<<32,   256, 0, stream>>>(eWih, eWhh, dWih, dWhh, euih, euhh, duih, duhh,
                                    uinv, vv, vss);
  k_sig  <<<512,  256, 0, stream>>>(eWih, eWhh, dWih, dWhh, vv, sgp);
  k_fin  <<<1,    64,  0, stream>>>(vss, sgp, rsig);
  k_pack <<<16384,256, 0, stream>>>(eWih, eWhh, dWih, dWhh, rsig, Wpe, Wpd);
  k_packb<<<64,   256, 0, stream>>>(eb, db, bp);
  k_xb   <<<4096, 512, 0, stream>>>(x, xb);
  k_xd0  <<<16,   512, 0, stream>>>(initial, xd0);

  float* out = (float*)d_out;
  float* muo = out + (long)B_ * T_ * D_;
  float* sgo = muo + 4l * B_ * G_;

  persist<<<NWG, 512, 0, stream>>>(Wpe, Wpd, bp, xb, xd0,
                                   ring0, ring1,
                                   ce0, ce1, hd0i, hd1i, cd0, cd1,
                                   hmuW, hmub, hsgW, hsgb, houtW, houtb,
                                   cmuW, cmub, csgW, csgb, coutW, coutb,
                                   eps_h, eps_c, out, muo, sgo, bar);
}

// Round 15
// 4725.196 us; speedup vs baseline: 2.3166x; 1.0627x over previous
//
#include <hip/hip_runtime.h>

// LSTM-VAE  B=64 T=256 D=1024 L=2 G=128 — persistent kernel, signal-driven.
// Round 15: PREFIX-POLLING — poller wave polls all 8 chunk lines per
// iteration, ballots, publishes longest complete prefix in one shot.
// Removes the serialized per-chunk LLC detect chain.
#define B_  64
#define T_  256
#define D_  1024
#define G_  128
#define FD  4096   // 4*D
#define K2  2048   // D (ih) + D (hh)
#define BD  65536  // B_*D_
#define NWG 256
#define CL  128    // u32 stride between counter lines (512 B)

typedef unsigned short u16;
typedef __attribute__((ext_vector_type(8))) short frag8;  // 8 bf16
typedef __attribute__((ext_vector_type(4))) float f4;
typedef __attribute__((ext_vector_type(4))) int i4;

__device__ __forceinline__ u16 f2b(float f) {
  unsigned u = __float_as_uint(f);
  u += 0x7fffu + ((u >> 16) & 1u);
  return (u16)(u >> 16);
}
__device__ __forceinline__ float b2f(u16 s) {
  return __uint_as_float(((unsigned)s) << 16);
}
__device__ __forceinline__ float sigm(float x) { return 1.0f / (1.0f + __expf(-x)); }

// write-through coherent 16B store (lands at LLC once vmcnt drains)
__device__ __forceinline__ void stcoh4(void* p, i4 w) {
  asm volatile("global_store_dwordx4 %0, %1, off sc0 sc1"
               :: "v"(p), "v"(w) : "memory");
}

// ---------------- group-signal primitives -----------------------------------
// Prefix poller: lanes 0..7 poll lines [base, base+8) every iteration; chunk c
// (c=0..3) ready iff lines 2c,2c+1 >= tgt. Publishes fb+prefix monotonically
// to the LDS flag; returns once prefix >= need. `pub` caches published prefix.
__device__ __forceinline__ void pollpre(const unsigned* s, int base,
                                        unsigned tgt, unsigned* lf,
                                        unsigned fb, unsigned need,
                                        unsigned& pub) {
  if (pub >= need) return;
  const int l = threadIdx.x & 63;
  for (;;) {
    bool ok = true;
    if (l < 8)
      ok = __hip_atomic_load(&s[(base + l) * CL], __ATOMIC_RELAXED,
                             __HIP_MEMORY_SCOPE_AGENT) >= tgt;
    unsigned long long m = __ballot(ok);
    unsigned p = 0;
    while (p < 4u && ((m >> (2 * p)) & 3ull) == 3ull) ++p;
    if (p > pub) {
      if (l == 0)
        __hip_atomic_store(lf, fb + p, __ATOMIC_RELAXED,
                           __HIP_MEMORY_SCOPE_WORKGROUP);
      pub = p;
    }
    if (pub >= need) break;
    __builtin_amdgcn_s_sleep(1);
  }
  asm volatile("" ::: "memory");
}

// lanes 0..15 poll all 16 lines; publish val to LDS flag (single-shot gate).
__device__ __forceinline__ void poll16_pub(const unsigned* s, unsigned tgt,
                                           unsigned* lf, unsigned val) {
  const int l = threadIdx.x & 63;
  for (;;) {
    bool ok = true;
    if (l < 16)
      ok = __hip_atomic_load(&s[l * CL], __ATOMIC_RELAXED,
                             __HIP_MEMORY_SCOPE_AGENT) >= tgt;
    if (__all(ok)) break;
    __builtin_amdgcn_s_sleep(1);
  }
  if (l == 0)
    __hip_atomic_store(lf, val, __ATOMIC_RELAXED, __HIP_MEMORY_SCOPE_WORKGROUP);
  asm volatile("" ::: "memory");
}

// Sibling waves: spin on the LDS flag (no fabric traffic).
__device__ __forceinline__ void lds_wait(const unsigned* lf, unsigned seq) {
  while (__hip_atomic_load(lf, __ATOMIC_RELAXED,
                           __HIP_MEMORY_SCOPE_WORKGROUP) < seq)
    __builtin_amdgcn_s_sleep(1);
  asm volatile("" ::: "memory");
}

// arrive: drain this WG's (coherent) stores, then one atomic add to `line`.
__device__ __forceinline__ void wg_arrive(unsigned* cnt, int line) {
  asm volatile("s_waitcnt vmcnt(0)" ::: "memory");
  __syncthreads();
  if (threadIdx.x == 0)
    __hip_atomic_fetch_add(&cnt[line * CL], 1u, __ATOMIC_RELAXED,
                           __HIP_MEMORY_SCOPE_AGENT);
}

// full-wave poll for phase-edge syncs (rare)
__device__ __forceinline__ void wave_wait16(const unsigned* cnt, unsigned tgt) {
  const int l = threadIdx.x & 63;
  if (l < 16) {
    while (__hip_atomic_load(&cnt[l * CL], __ATOMIC_RELAXED,
                             __HIP_MEMORY_SCOPE_AGENT) < tgt)
      __builtin_amdgcn_s_sleep(2);
  }
  asm volatile("" ::: "memory");
}

// full-grid sync (phase edges only); fenced = release/acquire cache ops
__device__ __forceinline__ void fullsync(unsigned* g, unsigned ep, int wg,
                                         bool fenced) {
  if (fenced) __builtin_amdgcn_fence(__ATOMIC_RELEASE, "agent");
  wg_arrive(g, wg & 15);
  wave_wait16(g, ep * 16u);
  __syncthreads();
  if (fenced) {
    __builtin_amdgcn_fence(__ATOMIC_ACQUIRE, "agent");
    __syncthreads();
  }
}

// ---------------- weight slice load: 32 rows x 2048 bf16, XOR-swizzled ------
__device__ __forceinline__ void load_weights(const u16* __restrict__ Wg, char* wlds) {
  const int t  = threadIdx.x;
  const int r  = t >> 4;           // 0..31
  const int c0 = t & 15;
  const char* src = (const char*)(Wg + (long)r * K2);
  char* dstrow = wlds + (r << 12);
  const int swz = (r & 7) << 4;
  #pragma unroll
  for (int i = 0; i < 16; ++i) {
    const int cb = (c0 + (i << 4)) << 4;      // chunk byte offset
    frag8 v = *(const frag8*)(src + cb);
    *(frag8*)(dstrow + (cb ^ swz)) = v;
  }
  __syncthreads();
}

// ---------------- one LSTM cell, prefix-polled 8-chunk waits ----------------
// A operands PERMUTED: A[(m*64+row)*8+u]. Wave (mt=wv&3, ks=wv>>2) covers rows
// mt*16..+16 and kk slice [ks*16, ks*16+16) of EACH operand.
// A1 = own-group operand, single gate (c1p,t1). A0 = cross-group operand,
// 8-chunk gate (c0p,t0): chunk cc (kk 4cc..4cc+4) gated by lines [2cc,2cc+2).
// a0half: weight K-half of A0. Flags: lsf[0]=A0ks0, lsf[1]=A0ks1, lsf[2]=A1.
__device__ __forceinline__ void cellw(
    const u16* __restrict__ A0, const unsigned* c0p, unsigned t0, int a0half,
    const u16* __restrict__ A1, const unsigned* c1p, unsigned t1,
    const char* wlds, float* gl, unsigned* lsf, unsigned seq,
    float& c_reg, const f4& bias, int ug0,
    u16* __restrict__ hout, float* __restrict__ fout, long fstride)
{
  const int tid = threadIdx.x;
  const int lane = tid & 63, wv = tid >> 6;
  const int mt = wv & 3, ks = wv >> 2;
  const int l15 = lane & 15, lgr = lane >> 4;

  f4 acc0 = (f4){0.f,0.f,0.f,0.f}, acc1 = (f4){0.f,0.f,0.f,0.f};
  const int lbase = (lgr * 64 + mt * 16 + l15) * 8;
  const int kwb = lgr << 4;
  const int swz = (l15 & 7) << 4;
  const char* w0r = wlds + ((long)l15 << 12);
  const char* w1r = wlds + ((long)(16 + l15) << 12);
  const int kk0 = ks * 16;

#define MM1(AP, HB, KK) {                                                      \
    frag8 af = *(const frag8*)((AP) + lbase + (KK) * 2048);                    \
    const int kb = ((HB) + ((KK) << 6) + kwb) ^ swz;                           \
    frag8 b0 = *(const frag8*)(w0r + kb);                                      \
    frag8 b1 = *(const frag8*)(w1r + kb);                                      \
    acc0 = __builtin_amdgcn_mfma_f32_16x16x32_bf16(af, b0, acc0, 0, 0, 0);     \
    acc1 = __builtin_amdgcn_mfma_f32_16x16x32_bf16(af, b1, acc1, 0, 0, 0); }

  // ---- A1 (own-group / free) first: 16 kk, single gate ----
  if (A1) {
    const int hb1 = (1 - a0half) << 11;
    if (c1p) {
      if (wv == 0) poll16_pub(c1p, t1, &lsf[2], seq);
      else         lds_wait(&lsf[2], seq);
    }
    #pragma unroll 8
    for (int kk = kk0; kk < kk0 + 16; ++kk) MM1(A1, hb1, kk)
  }
  // ---- A0 (cross-group / gated): 16 kk, 4 chunks of 4 kk, prefix-polled ----
  if (A0) {
    const int hb0 = a0half << 11;
    if (c0p) {
      const unsigned fb = 4u * (seq - 1u);
      unsigned* lf = &lsf[ks];
      unsigned pub = 0;
      #pragma unroll
      for (int cl = 0; cl < 4; ++cl) {
        const int cc = ks * 4 + cl;
        if (mt == 0) pollpre(c0p, ks * 8, t0, lf, fb, (unsigned)(cl + 1), pub);
        else         lds_wait(lf, fb + (unsigned)cl + 1u);
        #pragma unroll
        for (int kk = cc * 4; kk < cc * 4 + 4; ++kk) MM1(A0, hb0, kk)
      }
    } else {
      #pragma unroll 8
      for (int kk = kk0; kk < kk0 + 16; ++kk) MM1(A0, hb0, kk)
    }
  }
#undef MM1

  float* g = gl + ks * (64 * 32);
  const int orow = mt * 16 + lgr * 4;
  #pragma unroll
  for (int r = 0; r < 4; ++r) {
    g[(orow + r) * 32 + l15]      = acc0[r];
    g[(orow + r) * 32 + 16 + l15] = acc1[r];
  }
  __syncthreads();

  const int row = tid >> 3, ul = tid & 7;
  f4 p0 = *(const f4*)(gl + row * 32 + ul * 4);
  f4 p1 = *(const f4*)(gl + 64 * 32 + row * 32 + ul * 4);
  float iv = p0.x + p1.x + bias.x;
  float fv = p0.y + p1.y + bias.y;
  float gv = p0.z + p1.z + bias.z;
  float ov = p0.w + p1.w + bias.w;
  float cn = sigm(fv) * c_reg + sigm(iv) * tanhf(gv);
  float hh = sigm(ov) * tanhf(cn);
  c_reg = cn;
  // pack the 8-unit row (16B); one coherent dwordx4 per row (ul==0)
  unsigned hv = (unsigned)f2b(hh);
  unsigned a  = hv | (__shfl_xor(hv, 1) << 16);
  unsigned b  = __shfl_xor(a, 2);
  unsigned c2 = __shfl_xor(a, 4);
  unsigned d2 = __shfl_xor(b, 4);
  if (ul == 0) {
    i4 w; w.x = (int)a; w.y = (int)b; w.z = (int)c2; w.w = (int)d2;
    stcoh4(hout + ug0 * 64 + row * 8, w);
  }
  if (fout) fout[(long)row * fstride + ug0 + ul] = hh;
  // NOTE: gl WAR protection comes from wg_arrive()'s __syncthreads.
}

// ---------------- VAE head, one (s,l,b) per WG ------------------------------
// h inputs/outputs PERMUTED; c natural.
__device__ __forceinline__ void vae_wg(
    int bid, char* scr,
    const u16* h0f, const u16* h1f, const float* c0f, const float* c1f,
    const float* hmuW, const float* hmub, const float* hsgW, const float* hsgb,
    const float* houtW, const float* houtb,
    const float* cmuW, const float* cmub, const float* csgW, const float* csgb,
    const float* coutW, const float* coutb,
    const float* eps_h, const float* eps_c,
    float* muo, float* sgo, u16* hd0, u16* hd1, float* cd0, float* cd1)
{
  float* hrow = (float*)scr;
  float* muv  = hrow + 1024;
  float* sgv  = muv + 128;
  float* zz   = sgv + 128;
  const int tid = threadIdx.x;
  const int b = bid & 63, l = (bid >> 6) & 1, s = bid >> 7;

  if (s == 0) {
    const u16* h = l ? h1f : h0f;
    for (int i = tid; i < D_; i += 512)
      hrow[i] = b2f(h[(i >> 3) * 512 + b * 8 + (i & 7)]);
  } else {
    const float* c = (l ? c1f : c0f) + b * D_;
    for (int i = tid; i < D_; i += 512) hrow[i] = c[i];
  }
  __syncthreads();

  const float* muW = (s ? cmuW : hmuW) + (long)l * G_ * D_;
  const float* sgW = (s ? csgW : hsgW) + (long)l * G_ * D_;
  const float* mub = (s ? cmub : hmub) + l * G_;
  const float* sgb = (s ? csgb : hsgb) + l * G_;
  const int wv = tid >> 6, lane = tid & 63;
  for (int oi = wv; oi < 2 * G_; oi += 8) {
    const int g = (oi < G_) ? oi : oi - G_;
    const float* Wr = ((oi < G_) ? muW : sgW) + (long)g * D_;
    float d = 0.f;
    for (int j = lane; j < D_; j += 64) d += Wr[j] * hrow[j];
    for (int off = 1; off < 64; off <<= 1) d += __shfl_xor(d, off);
    if (lane == 0) {
      if (oi < G_) muv[g] = d + mub[g]; else sgv[g] = d + sgb[g];
    }
  }
  __syncthreads();
  if (tid < G_) {
    const int g = tid;
    const float mu = muv[g], sg = sgv[g];
    const float* ep = (s ? eps_c : eps_h) + ((long)l * B_ + b) * G_;
    zz[g] = mu + ep[g] * __expf(sg);
    muo[(long)bid * G_ + g] = mu;
    sgo[(long)bid * G_ + g] = sg;
  }
  __syncthreads();
  const float* oW  = (s ? coutW : houtW) + (long)l * D_ * G_;
  const float* obv = (s ? coutb : houtb) + l * D_;
  for (int i = 0; i < 2; ++i) {
    const int dd = i * 512 + tid;
    float acc = obv[dd];
    const float* Wr = oW + (long)dd * G_;
    #pragma unroll 4
    for (int g = 0; g < G_; ++g) acc += zz[g] * Wr[g];
    if (s == 0) {
      (l ? hd1 : hd0)[(dd >> 3) * 512 + b * 8 + (dd & 7)] = f2b(acc);
    } else {
      (l ? cd1 : cd0)[b * D_ + dd] = acc;
    }
  }
  __syncthreads();
}

// ---------------- the persistent kernel -------------------------------------
__global__ __launch_bounds__(512, 1)
void persist(const u16* __restrict__ Wpe, const u16* __restrict__ Wpd,
             const float* __restrict__ bp,
             const u16* __restrict__ xb, const u16* __restrict__ xd0,
             u16* ring0, u16* ring1,
             float* ce0, float* ce1,
             u16* hd0i, u16* hd1i, float* cd0, float* cd1,
             const float* hmuW, const float* hmub, const float* hsgW, const float* hsgb,
             const float* houtW, const float* houtb,
             const float* cmuW, const float* cmub, const float* csgW, const float* csgb,
             const float* coutW, const float* coutb,
             const float* eps_h, const float* eps_c,
             float* out, float* muo, float* sgo, unsigned* bar)
{
  __shared__ __align__(16) char smem[147456 + 64]; // 128K weights + 16K + flags
  char*  wlds = smem;
  float* gl   = (float*)(smem + 131072);
  unsigned* lsf = (unsigned*)(smem + 147456);      // [0]=A0ks0 [1]=A0ks1 [2]=A1

  unsigned* gcnt = bar;
  unsigned* acnt = bar + 2048;
  unsigned* bcnt = bar + 4096;
  unsigned* ccnt = bar + 6144;
  unsigned* dcnt = bar + 8192;

  const int wg  = blockIdx.x;
  const bool isL0 = (wg < 128);
  const int wgL = wg & 127;
  const int ug0 = wgL * 8;
  const int tid = threadIdx.x;
  const int aline = wgL >> 3;       // arrival line = column chunk of this WG

  // ---- encoder phase (signal-driven, no grid barriers) ----
  if (tid == 0) { lsf[0] = 0; lsf[1] = 0; lsf[2] = 0; }  // load_weights syncs
  load_weights(Wpe + (isL0 ? 0l : (long)FD * K2) + (long)wgL * 32 * K2, wlds);
  f4 bias = *(const f4*)(bp + (isL0 ? 0 : FD) + (ug0 + (tid & 7)) * 4);
  float c_reg = 0.f;

  if (isL0) {
    // A0 = ring0[s-1] (h-half, own-group, CHUNK-gated); A1 = xb[s] (free)
    for (int s = 0; s < T_; ++s) {
      cellw(s ? (ring0 + (long)(s - 1) * BD) : nullptr,
            s ? acnt : nullptr, 8u * (unsigned)s, 1,
            xb + (long)s * BD, nullptr, 0,
            wlds, gl, lsf, (unsigned)(s + 1),
            c_reg, bias, ug0,
            ring0 + (long)s * BD, nullptr, 0);
      wg_arrive(acnt, aline);
    }
  } else {
    // A0 = ring0[t] (x-half, cross-group, CHUNK-gated); A1 = ring1[t-1] (own)
    for (int t = 0; t < T_; ++t) {
      cellw(ring0 + (long)t * BD, acnt, 8u * (unsigned)(t + 1), 0,
            t ? (ring1 + (long)(t - 1) * BD) : nullptr,
            t ? bcnt : nullptr, 8u * (unsigned)t,
            wlds, gl, lsf, (unsigned)(t + 1),
            c_reg, bias, ug0,
            ring1 + (long)t * BD, nullptr, 0);
      wg_arrive(bcnt, aline);
    }
  }
  // publish final c (normal stores; fenced sync follows)
  {
    const int row = tid >> 3, ul = tid & 7;
    (isL0 ? ce0 : ce1)[row * D_ + ug0 + ul] = c_reg;
  }
  fullsync(gcnt, 1, wg, true);

  // ---- VAE ----
  vae_wg(wg, (char*)gl,
         ring0 + 255l * BD, ring1 + 255l * BD, ce0, ce1,
         hmuW, hmub, hsgW, hsgb, houtW, houtb,
         cmuW, cmub, csgW, csgb, coutW, coutb,
         eps_h, eps_c, muo, sgo, hd0i, hd1i, cd0, cd1);
  fullsync(gcnt, 2, wg, true);   // also invalidates encoder-era ring lines

  // ---- decoder phase (signal-driven, 2 handoffs/step) ----
  if (tid == 0) { lsf[0] = 0; lsf[1] = 0; lsf[2] = 0; }  // load_weights syncs
  load_weights(Wpd + (isL0 ? 0l : (long)FD * K2) + (long)wgL * 32 * K2, wlds);
  bias = *(const f4*)(bp + 2 * FD + (isL0 ? 0 : FD) + (ug0 + (tid & 7)) * 4);
  {
    const int row = tid >> 3, ul = tid & 7;
    c_reg = (isL0 ? cd0 : cd1)[row * D_ + ug0 + ul];
  }

  if (isL0) {
    // A0 = y[t-1] (x-half, cross-group, CHUNK-gated); A1 = ring0[t-1] (own)
    for (int t = 0; t < T_; ++t) {
      cellw(t ? (ring1 + (long)(t - 1) * BD) : xd0,
            t ? dcnt : nullptr, 8u * (unsigned)t, 0,
            t ? (ring0 + (long)(t - 1) * BD) : hd0i,
            t ? ccnt : nullptr, 8u * (unsigned)t,
            wlds, gl, lsf, (unsigned)(t + 1),
            c_reg, bias, ug0,
            ring0 + (long)t * BD, nullptr, 0);
      wg_arrive(ccnt, aline);
    }
  } else {
    // A0 = ring0[t] (x-half, cross-group, CHUNK-gated); A1 = ring1[t-1] (own)
    for (int t = 0; t < T_; ++t) {
      cellw(ring0 + (long)t * BD, ccnt, 8u * (unsigned)(t + 1), 0,
            t ? (ring1 + (long)(t - 1) * BD) : hd1i,
            t ? dcnt : nullptr, 8u * (unsigned)t,
            wlds, gl, lsf, (unsigned)(t + 1),
            c_reg, bias, ug0,
            ring1 + (long)t * BD, out + (long)t * D_, (long)T_ * D_);
      wg_arrive(dcnt, aline);
    }
  }
}

// ---------------------------------------------------------------------------
// Spectral norm prepass (unchanged, verified)
// ---------------------------------------------------------------------------
__device__ __forceinline__ const float* selW(int m, const float* a, const float* b,
                                             const float* c, const float* d) {
  const float* W;
  switch (m >> 1) { case 0: W = a; break; case 1: W = b; break;
                    case 2: W = c; break; default: W = d; }
  return W + (long)(m & 1) * FD * D_;
}
__device__ __forceinline__ const float* selU(int m, const float* a, const float* b,
                                             const float* c, const float* d) {
  const float* u;
  switch (m >> 1) { case 0: u = a; break; case 1: u = b; break;
                    case 2: u = c; break; default: u = d; }
  return u + (m & 1) * FD;
}

__global__ __launch_bounds__(256)
void k_unorm(const float* euih, const float* euhh, const float* duih, const float* duhh,
             float* uinv)
{
  const int m = blockIdx.x;
  const float* u = selU(m, euih, euhh, duih, duhh);
  float s = 0.f;
  for (int i = threadIdx.x; i < FD; i += 256) { float v = u[i]; s += v * v; }
  __shared__ float red[4];
  for (int off = 1; off < 64; off <<= 1) s += __shfl_xor(s, off);
  if ((threadIdx.x & 63) == 0) red[threadIdx.x >> 6] = s;
  __syncthreads();
  if (threadIdx.x == 0)
    uinv[m] = 1.0f / (sqrtf(red[0] + red[1] + red[2] + red[3]) + 1e-12f);
}

__global__ __launch_bounds__(256)
void k_v(const float* eWih, const float* eWhh, const float* dWih, const float* dWhh,
         const float* euih, const float* euhh, const float* duih, const float* duhh,
         const float* uinv, float* v, float* vss)
{
  __shared__ float us[FD];
  __shared__ float red[4];
  const int m = blockIdx.x >> 2, cb = blockIdx.x & 3;
  const float* W = selW(m, eWih, eWhh, dWih, dWhh);
  const float* u = selU(m, euih, euhh, duih, duhh);
  for (int i = threadIdx.x; i < FD; i += 256) us[i] = u[i];
  __syncthreads();
  const int j = cb * 256 + threadIdx.x;
  float acc = 0.f;
  for (int i = 0; i < FD; ++i) acc += W[(long)i * D_ + j] * us[i];
  acc *= uinv[m];
  v[m * D_ + j] = acc;
  float s = acc * acc;
  for (int off = 1; off < 64; off <<= 1) s += __shfl_xor(s, off);
  if ((threadIdx.x & 63) == 0) red[threadIdx.x >> 6] = s;
  __syncthreads();
  if (threadIdx.x == 0) vss[blockIdx.x] = red[0] + red[1] + red[2] + red[3];
}

__global__ __launch_bounds__(256)
void k_sig(const float* eWih, const float* eWhh, const float* dWih, const float* dWhh,
           const float* v, float* sgp)
{
  __shared__ float vl[D_];
  __shared__ float red[4];
  const int m = blockIdx.x >> 6, rb = blockIdx.x & 63;
  const float* W = selW(m, eWih, eWhh, dWih, dWhh);
  for (int i = threadIdx.x; i < D_; i += 256) vl[i] = v[m * D_ + i];
  __syncthreads();
  const int wv = threadIdx.x >> 6, lane = threadIdx.x & 63;
  float ssq = 0.f;
  for (int rr = 0; rr < 16; ++rr) {
    const int r = rb * 64 + wv * 16 + rr;
    const float* Wr = W + (long)r * D_;
    float d = 0.f;
    for (int j = lane; j < D_; j += 64) d += Wr[j] * vl[j];
    for (int off = 1; off < 64; off <<= 1) d += __shfl_xor(d, off);
    ssq += d * d;
  }
  if (lane == 0) red[wv] = ssq;
  __syncthreads();
  if (threadIdx.x == 0) sgp[blockIdx.x] = red[0] + red[1] + red[2] + red[3];
}

__global__ void k_fin(const float* vss, const float* sgp, float* rsig)
{
  const int m = threadIdx.x;
  if (m < 8) {
    float vn = sqrtf(vss[m * 4] + vss[m * 4 + 1] + vss[m * 4 + 2] + vss[m * 4 + 3]);
    float s2 = 0.f;
    for (int i = 0; i < 64; ++i) s2 += sgp[m * 64 + i];
    rsig[m] = (vn + 1e-12f) / sqrtf(s2);   // 1/sigma
  }
}

__global__ __launch_bounds__(256)
void k_pack(const float* eWih, const float* eWhh, const float* dWih, const float* dWhh,
            const float* rsig, u16* Wpe, u16* Wpd)
{
  const long idx = (long)blockIdx.x * 256 + threadIdx.x;
  const int k8   = (int)(idx & 255);
  const int np   = (int)((idx >> 8) & 4095);
  const int pair = (int)(idx >> 20);
  const int l = pair & 1, ed = pair >> 1;
  const int u = np >> 2, g = np & 3;
  const int srow = g * D_ + u;
  const int k = k8 * 8;
  const float* src; float sc;
  if (k < D_) {
    const float* Wih = ed ? dWih : eWih;
    src = Wih + ((long)(l * FD + srow)) * D_ + k;
    sc  = rsig[ed ? 4 + l : l];
  } else {
    const float* Whh = ed ? dWhh : eWhh;
    src = Whh + ((long)(l * FD + srow)) * D_ + (k - D_);
    sc  = rsig[ed ? 6 + l : 2 + l];
  }
  f4 a = *(const f4*)src;
  f4 b = *(const f4*)(src + 4);
  frag8 o;
  o[0] = (short)f2b(a.x * sc); o[1] = (short)f2b(a.y * sc);
  o[2] = (short)f2b(a.z * sc); o[3] = (short)f2b(a.w * sc);
  o[4] = (short)f2b(b.x * sc); o[5] = (short)f2b(b.y * sc);
  o[6] = (short)f2b(b.z * sc); o[7] = (short)f2b(b.w * sc);
  u16* dst = (ed ? Wpd : Wpe) + ((long)(l * FD + np)) * K2 + k;
  *(frag8*)dst = o;
}

__global__ void k_packb(const float* eb, const float* db, float* bp)
{
  const int idx = blockIdx.x * 256 + threadIdx.x;   // 4*4096
  const int j = idx & 4095, pair = idx >> 12;
  const int l = pair & 1, ed = pair >> 1;
  const float* b = (ed ? db : eb) + l * FD;
  bp[pair * FD + j] = b[(j & 3) * D_ + (j >> 2)];
}

// x [B,T,D] f32 -> xb PERMUTED: xb[t][(m*64+b)*8+u] = x[b][t][m*8+u]
__global__ __launch_bounds__(512)
void k_xb(const float* __restrict__ x, u16* __restrict__ xb)
{
  const long i8 = ((long)blockIdx.x * 512 + threadIdx.x) * 8;
  const int t   = (int)(i8 >> 16);           // / BD
  const int rem = (int)(i8 & 65535);
  const int m   = rem >> 9;
  const int b   = (rem >> 3) & 63;
  const float* src = x + ((long)b * T_ + t) * D_ + m * 8;
  f4 a = *(const f4*)src;
  f4 c = *(const f4*)(src + 4);
  frag8 o;
  o[0] = (short)f2b(a.x); o[1] = (short)f2b(a.y);
  o[2] = (short)f2b(a.z); o[3] = (short)f2b(a.w);
  o[4] = (short)f2b(c.x); o[5] = (short)f2b(c.y);
  o[6] = (short)f2b(c.z); o[7] = (short)f2b(c.w);
  *(frag8*)(xb + i8) = o;
}

// initial [1,D] -> xd0 PERMUTED broadcast over b
__global__ __launch_bounds__(512)
void k_xd0(const float* __restrict__ initial, u16* __restrict__ xd0)
{
  const int i8 = (blockIdx.x * 512 + threadIdx.x) * 8;   // < 65536
  const int m  = i8 >> 9;
  f4 a = *(const f4*)(initial + m * 8);
  f4 c = *(const f4*)(initial + m * 8 + 4);
  frag8 o;
  o[0] = (short)f2b(a.x); o[1] = (short)f2b(a.y);
  o[2] = (short)f2b(a.z); o[3] = (short)f2b(a.w);
  o[4] = (short)f2b(c.x); o[5] = (short)f2b(c.y);
  o[6] = (short)f2b(c.z); o[7] = (short)f2b(c.w);
  *(frag8*)(xd0 + i8) = o;
}

// ---------------------------------------------------------------------------
extern "C" void kernel_launch(void* const* d_in, const int* in_sizes, int n_in,
                              void* d_out, int out_size, void* d_ws, size_t ws_size,
                              hipStream_t stream)
{
  const float* x       = (const float*)d_in[0];
  const float* initial = (const float*)d_in[1];
  const float* eWih    = (const float*)d_in[2];
  const float* eWhh    = (const float*)d_in[3];
  const float* eb      = (const float*)d_in[4];
  const float* euih    = (const float*)d_in[5];
  const float* euhh    = (const float*)d_in[6];
  const float* dWih    = (const float*)d_in[7];
  const float* dWhh    = (const float*)d_in[8];
  const float* db      = (const float*)d_in[9];
  const float* duih    = (const float*)d_in[10];
  const float* duhh    = (const float*)d_in[11];
  const float* hmuW    = (const float*)d_in[12];
  const float* hmub    = (const float*)d_in[13];
  const float* hsgW    = (const float*)d_in[14];
  const float* hsgb    = (const float*)d_in[15];
  const float* houtW   = (const float*)d_in[16];
  const float* houtb   = (const float*)d_in[17];
  const float* cmuW    = (const float*)d_in[18];
  const float* cmub    = (const float*)d_in[19];
  const float* csgW    = (const float*)d_in[20];
  const float* csgb    = (const float*)d_in[21];
  const float* coutW   = (const float*)d_in[22];
  const float* coutb   = (const float*)d_in[23];
  const float* eps_h   = (const float*)d_in[24];
  const float* eps_c   = (const float*)d_in[25];

  char* w = (char*)d_ws;
  auto alloc = [&](size_t n) -> char* {
    char* p = w; w += (n + 255) & ~(size_t)255; return p;
  };
  u16*   Wpe   = (u16*)  alloc(2l * FD * K2 * 2);       // 32 MB
  u16*   Wpd   = (u16*)  alloc(2l * FD * K2 * 2);       // 32 MB
  u16*   xb    = (u16*)  alloc((long)T_ * BD * 2);      // 32 MB
  u16*   ring0 = (u16*)  alloc((long)T_ * BD * 2);      // 32 MB
  u16*   ring1 = (u16*)  alloc((long)T_ * BD * 2);      // 32 MB
  u16*   xd0   = (u16*)  alloc((long)BD * 2);
  u16*   hd0i  = (u16*)  alloc((long)BD * 2);
  u16*   hd1i  = (u16*)  alloc((long)BD * 2);
  float* ce0   = (float*)alloc((long)BD * 4);
  float* ce1   = (float*)alloc((long)BD * 4);
  float* cd0   = (float*)alloc((long)BD * 4);
  float* cd1   = (float*)alloc((long)BD * 4);
  float* bp    = (float*)alloc(4l * FD * 4);
  float* vv    = (float*)alloc(8l * D_ * 4);
  float* uinv  = (float*)alloc(64);
  float* vss   = (float*)alloc(256);
  float* sgp   = (float*)alloc(4096);
  float* rsig  = (float*)alloc(64);
  unsigned* bar = (unsigned*)alloc(40960);   // 5 sets x 16 lines x 512B

  hipMemsetAsync(bar, 0, 40960, stream);

  k_unorm<<<8,    256, 0, stream>>>(euih, euhh, duih, duhh, uinv);
  k_v    <<<32,   256, 0, stream>>>(eWih, eWhh, dWih, dWhh, euih, euhh, duih, duhh,
                                    uinv, vv, vss);
  k_sig  <<<512,  256, 0, stream>>>(eWih, eWhh, dWih, dWhh, vv, sgp);
  k_fin  <<<1,    64,  0, stream>>>(vss, sgp, rsig);
  k_pack <<<16384,256, 0, stream>>>(eWih, eWhh, dWih, dWhh, rsig, Wpe, Wpd);
  k_packb<<<64,   256, 0, stream>>>(eb, db, bp);
  k_xb   <<<4096, 512, 0, stream>>>(x, xb);
  k_xd0  <<<16,   512, 0, stream>>>(initial, xd0);

  float* out = (float*)d_out;
  float* muo = out + (long)B_ * T_ * D_;
  float* sgo = muo + 4l * B_ * G_;

  persist<<<NWG, 512, 0, stream>>>(Wpe, Wpd, bp, xb, xd0,
                                   ring0, ring1,
                                   ce0, ce1, hd0i, hd1i, cd0, cd1,
                                   hmuW, hmub, hsgW, hsgb, houtW, houtb,
                                   cmuW, cmub, csgW, csgb, coutW, coutb,
                                   eps_h, eps_c, out, muo, sgo, bar);
}